// Round 12
// baseline (145.434 us; speedup 1.0000x reference)
//
#include <hip/hip_runtime.h>

typedef unsigned short ushortT;
typedef _Float16 f16x8 __attribute__((ext_vector_type(8)));
typedef __fp16 fp16v2 __attribute__((ext_vector_type(2)));
typedef __attribute__((ext_vector_type(4))) float f32x4;

constexpr int B_ = 256, P_ = 32, N_ = 60;
constexpr int NE = N_ * (N_ - 1);          // 3540
constexpr int NETOT = B_ * NE;             // 906240
constexpr int ROWS = B_ * N_;              // 15360
constexpr float EPS = 1e-5f;

// ---- workspace layout (float offsets) ----
constexpr size_t F_XT  = 0;                          // ROWS*32
constexpr size_t F_EBAR = F_XT + (size_t)ROWS * 32;  // ROWS*32
constexpr size_t F_HO1 = F_EBAR + (size_t)ROWS * 32; // ROWS*64
constexpr size_t F_HO2 = F_HO1 + (size_t)ROWS * 64;  // ROWS*64
constexpr size_t F_HO3 = F_HO2 + (size_t)ROWS * 64;  // ROWS*32
constexpr size_t F_U   = F_HO3 + (size_t)ROWS * 32;  // ROWS*64 f32 (raw, no b1)
constexpr size_t F_V   = F_U + (size_t)ROWS * 64;    // ROWS*64 f32
constexpr size_t F_UH  = F_V + (size_t)ROWS * 64;    // ROWS*64 fp16 packed
constexpr size_t F_VH  = F_UH + (size_t)ROWS * 32;   // ROWS*64 fp16 packed
// stat accumulators: NO host memset. Direct-store slots where block->slot is
// unique; atomic slots are zeroed by the PRECEDING kernel in the chain.
constexpr size_t G_B   = F_VH + (size_t)ROWS * 32;
constexpr size_t G_INS = G_B;                  // 8 slots x 64   (direct store: k0)
constexpr size_t G_BN1 = G_INS + 8 * 64;       // 256 slots x 128 (direct store: k1)
constexpr size_t G_ST2 = G_BN1 + 256 * 128;    // 64 slots x 128 (atomic; zeroed in k3b)
constexpr size_t G_ST3 = G_ST2 + 64 * 128;     // 64 slots x 64  (atomic; zeroed in kedge1)
constexpr size_t G_SO1 = G_ST3 + 64 * 64;      // 16 slots x 128 (atomic; zeroed in kedge2)
constexpr size_t G_SO2 = G_SO1 + 16 * 128;     // 16 slots x 128 (atomic; zeroed in kedge3)
constexpr size_t G_SO3 = G_SO2 + 16 * 128;     // 16 slots x 64  (atomic; zeroed in kobj1)
constexpr size_t G_CNT = 8 * 64 + 256 * 128 + 64 * 128 + 64 * 64 + 16 * 128 + 16 * 128 + 16 * 64;
constexpr size_t F_TOTAL = G_B + G_CNT;

static __device__ __forceinline__ unsigned int cvtpk16(float lo, float hi) {
    union { fp16v2 h; unsigned int u; } r;
    r.h = __builtin_amdgcn_cvt_pkrtz(lo, hi);
    return r.u;
}
static __device__ __forceinline__ unsigned int hadd_relu(unsigned int a, unsigned int b) {
    unsigned int r;
    asm("v_pk_add_f16 %0, %1, %2\n\tv_pk_max_f16 %0, %0, 0"
        : "=v"(r) : "v"(a), "v"(b));
    return r;
}
static __device__ __forceinline__ f16x8 ldf16(const float* __restrict__ p) {
    float4 a = *reinterpret_cast<const float4*>(p);
    float4 b = *reinterpret_cast<const float4*>(p + 4);
    union { unsigned int u[4]; f16x8 v; } r;
    r.u[0] = cvtpk16(a.x, a.y); r.u[1] = cvtpk16(a.z, a.w);
    r.u[2] = cvtpk16(b.x, b.y); r.u[3] = cvtpk16(b.z, b.w);
    return r.v;
}
static __device__ __forceinline__ f16x8 erelu(uint4 uu, uint4 vv, bool ok) {
    union { unsigned int u[4]; f16x8 v; } r;
    r.u[0] = hadd_relu(uu.x, vv.x);
    r.u[1] = hadd_relu(uu.y, vv.y);
    r.u[2] = hadd_relu(uu.z, vv.z);
    r.u[3] = hadd_relu(uu.w, vv.w);
    if (!ok) { r.u[0] = 0u; r.u[1] = 0u; r.u[2] = 0u; r.u[3] = 0u; }
    return r.v;
}

// ---- K0: input BN raw stats (direct store, unique (seg,p) slot) ----
__global__ __launch_bounds__(256) void k0_part(const float* __restrict__ x,
                                               float* __restrict__ ws) {
    int p = blockIdx.x & 31, seg = blockIdx.x >> 5;
    float s = 0.f, q = 0.f;
    for (int idx = threadIdx.x; idx < 32 * N_; idx += 256) {
        int bb = seg * 32 + idx / N_;
        int n = idx - (idx / N_) * N_;
        float v = x[(size_t)(bb * P_ + p) * N_ + n];
        s += v; q += v * v;
    }
    for (int o = 32; o > 0; o >>= 1) { s += __shfl_down(s, o); q += __shfl_down(q, o); }
    __shared__ float rs[4], rq[4];
    int wid = threadIdx.x >> 6, lane = threadIdx.x & 63;
    if (lane == 0) { rs[wid] = s; rq[wid] = q; }
    __syncthreads();
    if (threadIdx.x == 0) {
        s = rs[0] + rs[1] + rs[2] + rs[3];
        q = rq[0] + rq[1] + rq[2] + rq[3];
        float* slot = ws + G_INS + (size_t)seg * 64;
        slot[p] = s;
        slot[32 + p] = q;
    }
}

// ---- K1: inline input-BN finalize (8-slot sum); U,V raw; xt; BN1 partial direct-store ----
__global__ __launch_bounds__(256) void k1_uv(const float* __restrict__ x,
                                             const float* __restrict__ w1,
                                             const float* __restrict__ bnx_g,
                                             const float* __restrict__ bnx_b,
                                             float* __restrict__ ws) {
    int b = blockIdx.x;
    __shared__ float xs[P_ * N_];
    __shared__ float w1t[64 * 65];
    __shared__ float sX[32], tX[32];
    __shared__ float rbn[4][5][64];
    const int t = threadIdx.x;
    if (t < 32) {
        float S = 0.f, Q = 0.f;
        #pragma unroll
        for (int s = 0; s < 8; ++s) {
            S += ws[G_INS + (size_t)s * 64 + t];
            Q += ws[G_INS + (size_t)s * 64 + 32 + t];
        }
        float inv = 1.f / (float)(B_ * N_);
        float mean = S * inv;
        float var = Q * inv - mean * mean;
        float sc = bnx_g[t] * rsqrtf(var + EPS);
        sX[t] = sc;
        tX[t] = bnx_b[t] - mean * sc;
    }
    for (int idx = t; idx < 64 * 64; idx += 256) {
        int k = idx >> 6, c = idx & 63;
        w1t[c * 65 + k] = w1[idx];
    }
    __syncthreads();
    for (int idx = t; idx < P_ * N_; idx += 256) {
        int p = idx / N_, n = idx - (idx / N_) * N_;
        xs[idx] = sX[p] * x[(size_t)(b * P_ + p) * N_ + n] + tX[p];
    }
    __syncthreads();
    for (int idx = t; idx < N_ * P_; idx += 256) {
        int n = idx / P_, p = idx - (idx / P_) * P_;
        ws[F_XT + (size_t)(b * N_ + n) * P_ + p] = xs[p * N_ + n];
    }
    const int k = t & 63, ph = t >> 6;
    float wu[32], wv[32];
    #pragma unroll
    for (int p = 0; p < 32; ++p) {
        wu[p] = w1t[p * 65 + k];
        wv[p] = w1t[(32 + p) * 65 + k];
    }
    float su = 0, sv = 0, suu = 0, svv = 0, suv = 0;
    for (int idx = t; idx < N_ * 64; idx += 256) {
        int n = idx >> 6;
        float u = 0.f, v = 0.f;
        #pragma unroll
        for (int p = 0; p < 32; ++p) {
            float xv = xs[p * N_ + n];
            u += xv * wu[p];
            v += xv * wv[p];
        }
        ws[F_U + (size_t)(b * N_ + n) * 64 + k] = u;
        ws[F_V + (size_t)(b * N_ + n) * 64 + k] = v;
        su += u; sv += v; suu += u * u; svv += v * v; suv += u * v;
    }
    rbn[ph][0][k] = su; rbn[ph][1][k] = sv; rbn[ph][2][k] = suu;
    rbn[ph][3][k] = svv; rbn[ph][4][k] = suv;
    __syncthreads();
    if (t < 64) {
        float S_u = 0, S_v = 0, Quu = 0, Qvv = 0, Quv = 0;
        #pragma unroll
        for (int p2 = 0; p2 < 4; ++p2) {
            S_u += rbn[p2][0][t]; S_v += rbn[p2][1][t]; Quu += rbn[p2][2][t];
            Qvv += rbn[p2][3][t]; Quv += rbn[p2][4][t];
        }
        float* slot = ws + G_BN1 + (size_t)b * 128;   // unique slot per block
        slot[t] = 59.f * (S_u + S_v);
        slot[64 + t] = 59.f * (Quu + Qvv) + 2.f * (S_u * S_v - Quv);
    }
}

// ---- K3b: inline BN1 finalize (256-slot sum); fold & convert U,V -> fp16; zero G_ST2 ----
__global__ __launch_bounds__(256) void k3b(const float* __restrict__ g,
                                           const float* __restrict__ be,
                                           float* __restrict__ ws) {
    __shared__ float sc[64], sh[64];
    const int t = threadIdx.x;
    if (blockIdx.x < 64 && t < 128) ws[G_ST2 + (size_t)blockIdx.x * 128 + t] = 0.f;
    if (t < 64) {
        float S = 0.f, Q = 0.f;
        for (int s = 0; s < 256; ++s) {
            S += ws[G_BN1 + (size_t)s * 128 + t];
            Q += ws[G_BN1 + (size_t)s * 128 + 64 + t];
        }
        float inv = 1.f / (float)NETOT;
        float mean = S * inv, var = Q * inv - mean * mean;
        float s_ = g[t] * rsqrtf(var + EPS);
        sc[t] = s_;
        sh[t] = be[t] - mean * s_;
    }
    __syncthreads();
    size_t gid = (size_t)blockIdx.x * 256 + t;      // 480*256 = ROWS*64/8
    size_t base = gid * 8;
    int k0 = (int)(gid & 7) << 3;
    float4 u0 = *reinterpret_cast<const float4*>(ws + F_U + base);
    float4 u1 = *reinterpret_cast<const float4*>(ws + F_U + base + 4);
    float4 v0 = *reinterpret_cast<const float4*>(ws + F_V + base);
    float4 v1 = *reinterpret_cast<const float4*>(ws + F_V + base + 4);
    uint4 ou, ov;
    ou.x = cvtpk16(sc[k0+0]*u0.x + sh[k0+0], sc[k0+1]*u0.y + sh[k0+1]);
    ou.y = cvtpk16(sc[k0+2]*u0.z + sh[k0+2], sc[k0+3]*u0.w + sh[k0+3]);
    ou.z = cvtpk16(sc[k0+4]*u1.x + sh[k0+4], sc[k0+5]*u1.y + sh[k0+5]);
    ou.w = cvtpk16(sc[k0+6]*u1.z + sh[k0+6], sc[k0+7]*u1.w + sh[k0+7]);
    ov.x = cvtpk16(sc[k0+0]*v0.x, sc[k0+1]*v0.y);
    ov.y = cvtpk16(sc[k0+2]*v0.z, sc[k0+3]*v0.w);
    ov.z = cvtpk16(sc[k0+4]*v1.x, sc[k0+5]*v1.y);
    ov.w = cvtpk16(sc[k0+6]*v1.z, sc[k0+7]*v1.w);
    reinterpret_cast<uint4*>(ws + F_UH)[gid] = ou;
    reinterpret_cast<uint4*>(ws + F_VH)[gid] = ov;
}

// ---- KEDGE<STAGE>: 4 blocks/batch, 15 groups each, 1 group per wave, barrier-free ----
// STAGE1 zeroes G_ST3; STAGE2 zeroes G_SO1; STAGE3 zeroes G_SO2 (consumed downstream).
template <int STAGE>
__global__ __launch_bounds__(256, 4) void kedge(
    const float* __restrict__ fr2_w, const float* __restrict__ fr3_w,
    const float* __restrict__ g2, const float* __restrict__ be2,
    const float* __restrict__ g3, const float* __restrict__ be3,
    float* __restrict__ ws)
{
    __shared__ __align__(16) ushortT sUVh[75 * 72];   // rows 0..59 V', 60..74 U'
    __shared__ __align__(16) ushortT scrAll[4 * 1024];
    __shared__ float sBN[192];
    __shared__ float red[128];

    const int blk = blockIdx.x;
    const int b = blk >> 2, q = blk & 3;
    const int t = threadIdx.x;
    const int wv = t >> 6, lane = t & 63;
    const int gq = lane >> 4, ln = lane & 15;
    const f32x4 zero = {0.f, 0.f, 0.f, 0.f};

    if constexpr (STAGE == 1) {
        if (blk < 64 && t < 64) ws[G_ST3 + (size_t)blk * 64 + t] = 0.f;
    } else if constexpr (STAGE == 2) {
        if (blk < 16 && t < 128) ws[G_SO1 + (size_t)blk * 128 + t] = 0.f;
    } else {
        if (blk < 16 && t < 128) ws[G_SO2 + (size_t)blk * 128 + t] = 0.f;
    }

    {
        const ushortT* vh = reinterpret_cast<const ushortT*>(ws + F_VH) + (size_t)b * N_ * 64;
        const ushortT* uh = reinterpret_cast<const ushortT*>(ws + F_UH) + (size_t)(b * N_ + q * 15) * 64;
        for (int idx = t; idx < 480; idx += 256) {
            int r = idx >> 3, c = (idx & 7) << 3;
            *reinterpret_cast<uint4*>(&sUVh[r * 72 + c]) =
                *reinterpret_cast<const uint4*>(&vh[(size_t)r * 64 + c]);
        }
        if (t < 120) {
            int r = t >> 3, c = (t & 7) << 3;
            *reinterpret_cast<uint4*>(&sUVh[(60 + r) * 72 + c]) =
                *reinterpret_cast<const uint4*>(&uh[(size_t)r * 64 + c]);
        }
    }
    if constexpr (STAGE >= 2) {
        if (t < 64) {
            float S = 0.f, Q = 0.f;
            for (int s = 0; s < 64; ++s) {
                S += ws[G_ST2 + (size_t)s * 128 + t];
                Q += ws[G_ST2 + (size_t)s * 128 + 64 + t];
            }
            float inv = 1.f / (float)NETOT;
            float m = S * inv, var = Q * inv - m * m;
            float s_ = g2[t] * rsqrtf(var + EPS);
            sBN[t] = s_; sBN[64 + t] = be2[t] - m * s_;
        }
    }
    if constexpr (STAGE == 3) {
        if (t >= 64 && t < 96) {
            int tt = t - 64;
            float S = 0.f, Q = 0.f;
            for (int s = 0; s < 64; ++s) {
                S += ws[G_ST3 + (size_t)s * 64 + tt];
                Q += ws[G_ST3 + (size_t)s * 64 + 32 + tt];
            }
            float inv = 1.f / (float)NETOT;
            float m = S * inv, var = Q * inv - m * m;
            float s_ = g3[tt] * rsqrtf(var + EPS);
            sBN[128 + tt] = s_; sBN[160 + tt] = be3[tt] - m * s_;
        }
    }
    if (t < 128) red[t] = 0.f;

    // weight fragments -> registers (inline f32 -> fp16 conversion)
    f16x8 w2f0[4], w2f1[4], w3f0[2], w3f1[2];
    #pragma unroll
    for (int mu = 0; mu < 4; ++mu) {
        w2f0[mu] = ldf16(fr2_w + (size_t)(mu * 16 + ln) * 64 + gq * 8);
        w2f1[mu] = ldf16(fr2_w + (size_t)(mu * 16 + ln) * 64 + 32 + gq * 8);
    }
    if constexpr (STAGE >= 2) {
        #pragma unroll
        for (int nv = 0; nv < 2; ++nv) {
            w3f0[nv] = ldf16(fr3_w + (size_t)(nv * 16 + ln) * 64 + gq * 8);
            w3f1[nv] = ldf16(fr3_w + (size_t)(nv * 16 + ln) * 64 + 32 + gq * 8);
        }
    }
    __syncthreads();

    ushortT* scr = scrAll + wv * 1024;

    if constexpr (STAGE == 1) {
        f32x4 s1s[4] = {zero, zero, zero, zero};
        f32x4 s1q[4] = {zero, zero, zero, zero};
        for (int gi = wv; gi < 15; gi += 4) {
            const int i = q * 15 + gi;
            uint4 uu0 = *reinterpret_cast<const uint4*>(&sUVh[(60 + gi) * 72 + gq * 8]);
            uint4 uu1 = *reinterpret_cast<const uint4*>(&sUVh[(60 + gi) * 72 + 32 + gq * 8]);
            #pragma unroll
            for (int m = 0; m < 4; ++m) {
                int e = (m << 4) + ln;
                int j = e + (e >= i ? 1 : 0);
                uint4 vv0 = *reinterpret_cast<const uint4*>(&sUVh[j * 72 + gq * 8]);
                uint4 vv1 = *reinterpret_cast<const uint4*>(&sUVh[j * 72 + 32 + gq * 8]);
                f16x8 ef0 = erelu(uu0, vv0, e < 59);
                f16x8 ef1 = erelu(uu1, vv1, e < 59);
                #pragma unroll
                for (int mu = 0; mu < 4; ++mu) {
                    f32x4 acc = __builtin_amdgcn_mfma_f32_16x16x32_f16(w2f0[mu], ef0, zero, 0, 0, 0);
                    acc = __builtin_amdgcn_mfma_f32_16x16x32_f16(w2f1[mu], ef1, acc, 0, 0, 0);
                    s1s[mu] += acc;
                    s1q[mu] += acc * acc;
                }
            }
        }
        #pragma unroll
        for (int off = 1; off <= 8; off <<= 1)
            #pragma unroll
            for (int mu = 0; mu < 4; ++mu)
                #pragma unroll
                for (int r = 0; r < 4; ++r) {
                    s1s[mu][r] += __shfl_xor(s1s[mu][r], off);
                    s1q[mu][r] += __shfl_xor(s1q[mu][r], off);
                }
        if (ln == 0) {
            #pragma unroll
            for (int mu = 0; mu < 4; ++mu)
                #pragma unroll
                for (int r = 0; r < 4; ++r) {
                    atomicAdd(&red[mu * 16 + gq * 4 + r], s1s[mu][r]);
                    atomicAdd(&red[64 + mu * 16 + gq * 4 + r], s1q[mu][r]);
                }
        }
        __syncthreads();
        if (t < 128) atomicAdd(ws + G_ST2 + (size_t)(blk & 63) * 128 + t, red[t]);
    } else {
        float st0 = 0.f, st1 = 0.f, st2 = 0.f, st3 = 0.f;
        const float s30 = sBN[128 + ln], s31 = sBN[144 + ln];
        const float t30 = sBN[160 + ln], t31 = sBN[176 + ln];
        for (int gi = wv; gi < 15; gi += 4) {
            const int i = q * 15 + gi;
            uint4 uu0 = *reinterpret_cast<const uint4*>(&sUVh[(60 + gi) * 72 + gq * 8]);
            uint4 uu1 = *reinterpret_cast<const uint4*>(&sUVh[(60 + gi) * 72 + 32 + gq * 8]);
            float es0 = 0.f, es1 = 0.f;
            #pragma unroll
            for (int m = 0; m < 4; ++m) {
                int e = (m << 4) + ln;
                int j = e + (e >= i ? 1 : 0);
                uint4 vv0 = *reinterpret_cast<const uint4*>(&sUVh[j * 72 + gq * 8]);
                uint4 vv1 = *reinterpret_cast<const uint4*>(&sUVh[j * 72 + 32 + gq * 8]);
                const bool eok = e < 59;
                f16x8 ef0 = erelu(uu0, vv0, eok);
                f16x8 ef1 = erelu(uu1, vv1, eok);
                f32x4 ac[4];
                #pragma unroll
                for (int mu = 0; mu < 4; ++mu) {
                    ac[mu] = __builtin_amdgcn_mfma_f32_16x16x32_f16(w2f0[mu], ef0, zero, 0, 0, 0);
                    ac[mu] = __builtin_amdgcn_mfma_f32_16x16x32_f16(w2f1[mu], ef1, ac[mu], 0, 0, 0);
                }
                // e2 = relu(bn2(h2)) -> per-wave LDS transpose scatter (verified mapping)
                #pragma unroll
                for (int mu = 0; mu < 4; ++mu) {
                    int fb = mu * 16 + (gq << 2);
                    float4 sc2 = *reinterpret_cast<const float4*>(sBN + fb);
                    float4 sh2 = *reinterpret_cast<const float4*>(sBN + 64 + fb);
                    unsigned int pk0 = cvtpk16(fmaxf(0.f, sc2.x * ac[mu][0] + sh2.x),
                                               fmaxf(0.f, sc2.y * ac[mu][1] + sh2.y));
                    unsigned int pk1 = cvtpk16(fmaxf(0.f, sc2.z * ac[mu][2] + sh2.z),
                                               fmaxf(0.f, sc2.w * ac[mu][3] + sh2.w));
                    if (!eok) { pk0 = 0u; pk1 = 0u; }
                    int lp = ln + ((((mu << 1) + (gq >> 1)) & 3) << 4);
                    int off = ((mu >> 1) << 9) + (lp << 3) + ((gq & 1) << 2);
                    uint2 pr; pr.x = pk0; pr.y = pk1;
                    *reinterpret_cast<uint2*>(&scr[off]) = pr;
                }
                __threadfence_block();
                union { uint4 q4; f16x8 v; } ea0, ea1;
                ea0.q4 = *reinterpret_cast<const uint4*>(&scr[lane << 3]);
                ea1.q4 = *reinterpret_cast<const uint4*>(&scr[512 + (lane << 3)]);
                f32x4 a30 = __builtin_amdgcn_mfma_f32_16x16x32_f16(ea0.v, w3f0[0], zero, 0, 0, 0);
                a30 = __builtin_amdgcn_mfma_f32_16x16x32_f16(ea1.v, w3f1[0], a30, 0, 0, 0);
                f32x4 a31 = __builtin_amdgcn_mfma_f32_16x16x32_f16(ea0.v, w3f0[1], zero, 0, 0, 0);
                a31 = __builtin_amdgcn_mfma_f32_16x16x32_f16(ea1.v, w3f1[1], a31, 0, 0, 0);
                if constexpr (STAGE == 2) {
                    #pragma unroll
                    for (int r = 0; r < 4; ++r) {
                        st0 += a30[r]; st1 += a30[r] * a30[r];
                        st2 += a31[r]; st3 += a31[r] * a31[r];
                    }
                } else {
                    #pragma unroll
                    for (int r = 0; r < 4; ++r) {
                        if ((m << 4) + (gq << 2) + r < 59) {
                            es0 += fmaxf(0.f, s30 * a30[r] + t30);
                            es1 += fmaxf(0.f, s31 * a31[r] + t31);
                        }
                    }
                }
            }
            if constexpr (STAGE == 3) {
                es0 += __shfl_xor(es0, 16); es0 += __shfl_xor(es0, 32);
                es1 += __shfl_xor(es1, 16); es1 += __shfl_xor(es1, 32);
                if (lane < 16) {
                    ws[F_EBAR + (size_t)(b * N_ + i) * 32 + ln] = es0;
                    ws[F_EBAR + (size_t)(b * N_ + i) * 32 + 16 + ln] = es1;
                }
            }
        }
        if constexpr (STAGE == 2) {
            st0 += __shfl_xor(st0, 16); st0 += __shfl_xor(st0, 32);
            st1 += __shfl_xor(st1, 16); st1 += __shfl_xor(st1, 32);
            st2 += __shfl_xor(st2, 16); st2 += __shfl_xor(st2, 32);
            st3 += __shfl_xor(st3, 16); st3 += __shfl_xor(st3, 32);
            if (lane < 16) {
                atomicAdd(&red[ln], st0);      atomicAdd(&red[16 + ln], st2);
                atomicAdd(&red[32 + ln], st1); atomicAdd(&red[48 + ln], st3);
            }
            __syncthreads();
            if (t < 64) atomicAdd(ws + G_ST3 + (size_t)(blk & 63) * 64 + t, red[t]);
        }
    }
}

// ---- object-path linear; optional inline BN finalize (16-slot sum); slotted output stats ----
// zeroPtr (if non-null): zero 16 slots x zeroStride floats (consumed by a LATER kernel)
template <int OUT, int FIN>
__global__ __launch_bounds__(256) void kobj(const float* __restrict__ srcA,
                                            const float* __restrict__ srcB,
                                            const float* __restrict__ statIn,
                                            const float* __restrict__ gP,
                                            const float* __restrict__ beP,
                                            const float* __restrict__ W,
                                            float* __restrict__ outp,
                                            float* __restrict__ statOut,
                                            float* __restrict__ zeroPtr,
                                            int zeroCnt) {
    constexpr int TRN = (OUT == 64) ? 16 : 32;
    constexpr int RB = 4 * TRN;
    constexpr int SP = RB + 4;
    constexpr int WP = OUT + 4;
    __shared__ __align__(16) float sinT[64 * SP];
    __shared__ __align__(16) float swt[64 * WP];
    __shared__ float sAct[128];
    const int t = threadIdx.x;
    const int row0 = blockIdx.x * RB;
    if (zeroPtr && (int)blockIdx.x < 16 && t < zeroCnt)
        zeroPtr[(size_t)blockIdx.x * zeroCnt + t] = 0.f;
    if (FIN > 0 && t < 64) {
        float S = 0.f, Q = 0.f;
        #pragma unroll
        for (int s = 0; s < 16; ++s) {
            S += statIn[(size_t)s * 128 + t];
            Q += statIn[(size_t)s * 128 + 64 + t];
        }
        float inv = 1.f / (float)ROWS;
        float m = S * inv, var = Q * inv - m * m;
        float sc = gP[t] * rsqrtf(var + EPS);
        sAct[t] = sc; sAct[64 + t] = beP[t] - m * sc;
    }
    __syncthreads();
    for (int idx = t; idx < RB * 64; idx += 256) {
        int r = idx % RB, k = idx / RB;
        float v;
        if (srcB) {
            v = (k < 32) ? srcA[(size_t)(row0 + r) * 32 + k]
                         : srcB[(size_t)(row0 + r) * 32 + (k - 32)];
        } else {
            v = srcA[(size_t)(row0 + r) * 64 + k];
        }
        if (FIN > 0) v = fmaxf(0.f, sAct[k] * v + sAct[64 + k]);
        sinT[k * SP + r] = v;
    }
    for (int idx = t; idx < OUT * 64; idx += 256) {
        int o = idx >> 6, k = idx & 63;
        swt[k * WP + o] = W[idx];
    }
    __syncthreads();
    const int tr = t % TRN, to = t / TRN;
    const int r0 = tr * 4, o0 = to * 4;
    float acc[4][4];
    #pragma unroll
    for (int a = 0; a < 4; ++a)
        #pragma unroll
        for (int c = 0; c < 4; ++c) acc[a][c] = 0.f;
    #pragma unroll 8
    for (int k = 0; k < 64; ++k) {
        float4 a4 = *reinterpret_cast<const float4*>(sinT + k * SP + r0);
        float4 w4 = *reinterpret_cast<const float4*>(swt + k * WP + o0);
        float av[4] = {a4.x, a4.y, a4.z, a4.w};
        float wv[4] = {w4.x, w4.y, w4.z, w4.w};
        #pragma unroll
        for (int a = 0; a < 4; ++a)
            #pragma unroll
            for (int c = 0; c < 4; ++c) acc[a][c] += av[a] * wv[c];
    }
    float lsum[4] = {0.f, 0.f, 0.f, 0.f}, lsq[4] = {0.f, 0.f, 0.f, 0.f};
    #pragma unroll
    for (int a = 0; a < 4; ++a) {
        float4 res;
        res.x = acc[a][0]; res.y = acc[a][1]; res.z = acc[a][2]; res.w = acc[a][3];
        #pragma unroll
        for (int c = 0; c < 4; ++c) { lsum[c] += acc[a][c]; lsq[c] += acc[a][c] * acc[a][c]; }
        *reinterpret_cast<float4*>(outp + (size_t)(row0 + r0 + a) * OUT + o0) = res;
    }
    #pragma unroll
    for (int o = TRN / 2; o >= 1; o >>= 1) {
        #pragma unroll
        for (int c = 0; c < 4; ++c) {
            lsum[c] += __shfl_down(lsum[c], o, TRN);
            lsq[c]  += __shfl_down(lsq[c], o, TRN);
        }
    }
    if (tr == 0) {
        float* so = statOut + (size_t)(blockIdx.x & 15) * (2 * OUT);
        #pragma unroll
        for (int c = 0; c < 4; ++c) {
            atomicAdd(so + o0 + c, lsum[c]);
            atomicAdd(so + OUT + o0 + c, lsq[c]);
        }
    }
}

// ---- K15: inline fin3 (16-slot sum); relu(bn(ho3)); pool; fc ----
__global__ __launch_bounds__(64) void k15_final(const float* __restrict__ g,
                                                const float* __restrict__ be,
                                                const float* __restrict__ fcw,
                                                const float* __restrict__ fcb,
                                                float* __restrict__ ws,
                                                float* __restrict__ out) {
    __shared__ float sc3s[32], sh3s[32];
    int b = blockIdx.x, t = threadIdx.x;
    if (t < 32) {
        float S = 0.f, Q = 0.f;
        #pragma unroll
        for (int s = 0; s < 16; ++s) {
            S += ws[G_SO3 + (size_t)s * 64 + t];
            Q += ws[G_SO3 + (size_t)s * 64 + 32 + t];
        }
        float inv = 1.f / (float)ROWS;
        float m = S * inv, var = Q * inv - m * m;
        float sc = g[t] * rsqrtf(var + EPS);
        sc3s[t] = sc; sh3s[t] = be[t] - m * sc;
    }
    __syncthreads();
    int f = t & 31, h = t >> 5;
    float sc = sc3s[f], sh = sh3s[f];
    float acc = 0.f;
    for (int n = h; n < N_; n += 2) {
        float v = ws[F_HO3 + (size_t)(b * N_ + n) * 32 + f];
        acc += fmaxf(0.f, sc * v + sh);
    }
    acc += __shfl_down(acc, 32);
    float p0 = acc * fcw[f];
    float p1 = acc * fcw[32 + f];
    #pragma unroll
    for (int o = 16; o >= 1; o >>= 1) {
        p0 += __shfl_xor(p0, o);
        p1 += __shfl_xor(p1, o);
    }
    if (t == 0) {
        out[b * 2 + 0] = p0 + fcb[0];
        out[b * 2 + 1] = p1 + fcb[1];
    }
}

extern "C" void kernel_launch(void* const* d_in, const int* in_sizes, int n_in,
                              void* d_out, int out_size, void* d_ws, size_t ws_size,
                              hipStream_t stream) {
    const float* x      = (const float*)d_in[0];
    const float* bnx_g  = (const float*)d_in[1];
    const float* bnx_b  = (const float*)d_in[2];
    const float* fr1_w  = (const float*)d_in[3];
    const float* fr1_g  = (const float*)d_in[5];
    const float* fr1_be = (const float*)d_in[6];
    const float* fr2_w  = (const float*)d_in[7];
    const float* fr2_g  = (const float*)d_in[9];
    const float* fr2_be = (const float*)d_in[10];
    const float* fr3_w  = (const float*)d_in[11];
    const float* fr3_g  = (const float*)d_in[13];
    const float* fr3_be = (const float*)d_in[14];
    const float* fo1_w  = (const float*)d_in[15];
    const float* fo1_g  = (const float*)d_in[17];
    const float* fo1_be = (const float*)d_in[18];
    const float* fo2_w  = (const float*)d_in[19];
    const float* fo2_g  = (const float*)d_in[21];
    const float* fo2_be = (const float*)d_in[22];
    const float* fo3_w  = (const float*)d_in[23];
    const float* fo3_g  = (const float*)d_in[25];
    const float* fo3_be = (const float*)d_in[26];
    const float* fc_w   = (const float*)d_in[27];
    const float* fc_b   = (const float*)d_in[28];

    float* ws = (float*)d_ws;
    float* out = (float*)d_out;
    if (ws_size < F_TOTAL * sizeof(float)) return;

    k0_part<<<256, 256, 0, stream>>>(x, ws);
    k1_uv<<<B_, 256, 0, stream>>>(x, fr1_w, bnx_g, bnx_b, ws);
    k3b<<<480, 256, 0, stream>>>(fr1_g, fr1_be, ws);
    kedge<1><<<B_ * 4, 256, 0, stream>>>(fr2_w, fr3_w, fr2_g, fr2_be, fr3_g, fr3_be, ws);
    kedge<2><<<B_ * 4, 256, 0, stream>>>(fr2_w, fr3_w, fr2_g, fr2_be, fr3_g, fr3_be, ws);
    kedge<3><<<B_ * 4, 256, 0, stream>>>(fr2_w, fr3_w, fr2_g, fr2_be, fr3_g, fr3_be, ws);
    kobj<64, 0><<<ROWS / 64, 256, 0, stream>>>(ws + F_XT, ws + F_EBAR, nullptr, nullptr, nullptr,
                                               fo1_w, ws + F_HO1, ws + G_SO1, ws + G_SO3, 64);
    kobj<64, 64><<<ROWS / 64, 256, 0, stream>>>(ws + F_HO1, nullptr, ws + G_SO1, fo1_g, fo1_be,
                                                fo2_w, ws + F_HO2, ws + G_SO2, nullptr, 0);
    kobj<32, 64><<<ROWS / 128, 256, 0, stream>>>(ws + F_HO2, nullptr, ws + G_SO2, fo2_g, fo2_be,
                                                 fo3_w, ws + F_HO3, ws + G_SO3, nullptr, 0);
    k15_final<<<B_, 64, 0, stream>>>(fo3_g, fo3_be, fc_w, fc_b, ws, out);
}

// Round 13
// 142.735 us; speedup vs baseline: 1.0189x; 1.0189x over previous
//
#include <hip/hip_runtime.h>

typedef unsigned short ushortT;
typedef _Float16 f16x8 __attribute__((ext_vector_type(8)));
typedef __fp16 fp16v2 __attribute__((ext_vector_type(2)));
typedef __attribute__((ext_vector_type(4))) float f32x4;

constexpr int B_ = 256, P_ = 32, N_ = 60;
constexpr int NE = N_ * (N_ - 1);          // 3540
constexpr int NETOT = B_ * NE;             // 906240
constexpr int ROWS = B_ * N_;              // 15360
constexpr float EPS = 1e-5f;

// ---- workspace layout (float offsets) ----
constexpr size_t F_XT  = 0;                          // ROWS*32
constexpr size_t F_EBAR = F_XT + (size_t)ROWS * 32;  // ROWS*32
constexpr size_t F_HO1 = F_EBAR + (size_t)ROWS * 32; // ROWS*64
constexpr size_t F_HO2 = F_HO1 + (size_t)ROWS * 64;  // ROWS*64
constexpr size_t F_HO3 = F_HO2 + (size_t)ROWS * 64;  // ROWS*32
constexpr size_t F_U   = F_HO3 + (size_t)ROWS * 32;  // ROWS*64 f32 (raw, no b1)
constexpr size_t F_V   = F_U + (size_t)ROWS * 64;    // ROWS*64 f32
constexpr size_t F_UH  = F_V + (size_t)ROWS * 64;    // ROWS*64 fp16 packed
constexpr size_t F_VH  = F_UH + (size_t)ROWS * 32;   // ROWS*64 fp16 packed
constexpr size_t F_H3  = F_VH + (size_t)ROWS * 32;   // NETOT*32 fp16 = NETOT*16 floats
// stat accumulators: NO host memset. Direct-store slots where block->slot is
// unique; atomic slots are zeroed by a PRECEDING kernel in the chain.
constexpr size_t G_B   = F_H3 + (size_t)NETOT * 16;
constexpr size_t G_INS = G_B;                  // 8 slots x 64   (direct store: k0)
constexpr size_t G_BN1 = G_INS + 8 * 64;       // 256 slots x 128 (direct store: k1)
constexpr size_t G_ST2 = G_BN1 + 256 * 128;    // 64 slots x 128 (atomic; zeroed in k3b)
constexpr size_t G_ST3 = G_ST2 + 64 * 128;     // 64 slots x 64  (atomic; zeroed in kedge1)
constexpr size_t G_SO1 = G_ST3 + 64 * 64;      // 16 slots x 128 (atomic; zeroed in kedge2)
constexpr size_t G_SO2 = G_SO1 + 16 * 128;     // 16 slots x 128 (atomic; zeroed in k8)
constexpr size_t G_SO3 = G_SO2 + 16 * 128;     // 16 slots x 64  (atomic; zeroed in kobj1)
constexpr size_t G_CNT = 8 * 64 + 256 * 128 + 64 * 128 + 64 * 64 + 16 * 128 + 16 * 128 + 16 * 64;
constexpr size_t F_TOTAL = G_B + G_CNT;

static __device__ __forceinline__ unsigned int cvtpk16(float lo, float hi) {
    union { fp16v2 h; unsigned int u; } r;
    r.h = __builtin_amdgcn_cvt_pkrtz(lo, hi);
    return r.u;
}
static __device__ __forceinline__ unsigned int hadd_relu(unsigned int a, unsigned int b) {
    unsigned int r;
    asm("v_pk_add_f16 %0, %1, %2\n\tv_pk_max_f16 %0, %0, 0"
        : "=v"(r) : "v"(a), "v"(b));
    return r;
}
static __device__ __forceinline__ f16x8 ldf16(const float* __restrict__ p) {
    float4 a = *reinterpret_cast<const float4*>(p);
    float4 b = *reinterpret_cast<const float4*>(p + 4);
    union { unsigned int u[4]; f16x8 v; } r;
    r.u[0] = cvtpk16(a.x, a.y); r.u[1] = cvtpk16(a.z, a.w);
    r.u[2] = cvtpk16(b.x, b.y); r.u[3] = cvtpk16(b.z, b.w);
    return r.v;
}
static __device__ __forceinline__ f16x8 erelu(uint4 uu, uint4 vv, bool ok) {
    union { unsigned int u[4]; f16x8 v; } r;
    r.u[0] = hadd_relu(uu.x, vv.x);
    r.u[1] = hadd_relu(uu.y, vv.y);
    r.u[2] = hadd_relu(uu.z, vv.z);
    r.u[3] = hadd_relu(uu.w, vv.w);
    if (!ok) { r.u[0] = 0u; r.u[1] = 0u; r.u[2] = 0u; r.u[3] = 0u; }
    return r.v;
}

// ---- K0: input BN raw stats (direct store, unique (seg,p) slot) ----
__global__ __launch_bounds__(256) void k0_part(const float* __restrict__ x,
                                               float* __restrict__ ws) {
    int p = blockIdx.x & 31, seg = blockIdx.x >> 5;
    float s = 0.f, q = 0.f;
    for (int idx = threadIdx.x; idx < 32 * N_; idx += 256) {
        int bb = seg * 32 + idx / N_;
        int n = idx - (idx / N_) * N_;
        float v = x[(size_t)(bb * P_ + p) * N_ + n];
        s += v; q += v * v;
    }
    for (int o = 32; o > 0; o >>= 1) { s += __shfl_down(s, o); q += __shfl_down(q, o); }
    __shared__ float rs[4], rq[4];
    int wid = threadIdx.x >> 6, lane = threadIdx.x & 63;
    if (lane == 0) { rs[wid] = s; rq[wid] = q; }
    __syncthreads();
    if (threadIdx.x == 0) {
        s = rs[0] + rs[1] + rs[2] + rs[3];
        q = rq[0] + rq[1] + rq[2] + rq[3];
        float* slot = ws + G_INS + (size_t)seg * 64;
        slot[p] = s;
        slot[32 + p] = q;
    }
}

// ---- K1: inline input-BN finalize (8-slot sum); U,V raw; xt; BN1 partial direct-store ----
__global__ __launch_bounds__(256) void k1_uv(const float* __restrict__ x,
                                             const float* __restrict__ w1,
                                             const float* __restrict__ bnx_g,
                                             const float* __restrict__ bnx_b,
                                             float* __restrict__ ws) {
    int b = blockIdx.x;
    __shared__ float xs[P_ * N_];
    __shared__ float w1t[64 * 65];
    __shared__ float sX[32], tX[32];
    __shared__ float rbn[4][5][64];
    const int t = threadIdx.x;
    if (t < 32) {
        float S = 0.f, Q = 0.f;
        #pragma unroll
        for (int s = 0; s < 8; ++s) {
            S += ws[G_INS + (size_t)s * 64 + t];
            Q += ws[G_INS + (size_t)s * 64 + 32 + t];
        }
        float inv = 1.f / (float)(B_ * N_);
        float mean = S * inv;
        float var = Q * inv - mean * mean;
        float sc = bnx_g[t] * rsqrtf(var + EPS);
        sX[t] = sc;
        tX[t] = bnx_b[t] - mean * sc;
    }
    for (int idx = t; idx < 64 * 64; idx += 256) {
        int k = idx >> 6, c = idx & 63;
        w1t[c * 65 + k] = w1[idx];
    }
    __syncthreads();
    for (int idx = t; idx < P_ * N_; idx += 256) {
        int p = idx / N_, n = idx - (idx / N_) * N_;
        xs[idx] = sX[p] * x[(size_t)(b * P_ + p) * N_ + n] + tX[p];
    }
    __syncthreads();
    for (int idx = t; idx < N_ * P_; idx += 256) {
        int n = idx / P_, p = idx - (idx / P_) * P_;
        ws[F_XT + (size_t)(b * N_ + n) * P_ + p] = xs[p * N_ + n];
    }
    const int k = t & 63, ph = t >> 6;
    float wu[32], wv[32];
    #pragma unroll
    for (int p = 0; p < 32; ++p) {
        wu[p] = w1t[p * 65 + k];
        wv[p] = w1t[(32 + p) * 65 + k];
    }
    float su = 0, sv = 0, suu = 0, svv = 0, suv = 0;
    for (int idx = t; idx < N_ * 64; idx += 256) {
        int n = idx >> 6;
        float u = 0.f, v = 0.f;
        #pragma unroll
        for (int p = 0; p < 32; ++p) {
            float xv = xs[p * N_ + n];
            u += xv * wu[p];
            v += xv * wv[p];
        }
        ws[F_U + (size_t)(b * N_ + n) * 64 + k] = u;
        ws[F_V + (size_t)(b * N_ + n) * 64 + k] = v;
        su += u; sv += v; suu += u * u; svv += v * v; suv += u * v;
    }
    rbn[ph][0][k] = su; rbn[ph][1][k] = sv; rbn[ph][2][k] = suu;
    rbn[ph][3][k] = svv; rbn[ph][4][k] = suv;
    __syncthreads();
    if (t < 64) {
        float S_u = 0, S_v = 0, Quu = 0, Qvv = 0, Quv = 0;
        #pragma unroll
        for (int p2 = 0; p2 < 4; ++p2) {
            S_u += rbn[p2][0][t]; S_v += rbn[p2][1][t]; Quu += rbn[p2][2][t];
            Qvv += rbn[p2][3][t]; Quv += rbn[p2][4][t];
        }
        float* slot = ws + G_BN1 + (size_t)b * 128;   // unique slot per block
        slot[t] = 59.f * (S_u + S_v);
        slot[64 + t] = 59.f * (Quu + Qvv) + 2.f * (S_u * S_v - Quv);
    }
}

// ---- K3b: inline BN1 finalize (256-slot sum); fold & convert U,V -> fp16; zero G_ST2 ----
__global__ __launch_bounds__(256) void k3b(const float* __restrict__ g,
                                           const float* __restrict__ be,
                                           float* __restrict__ ws) {
    __shared__ float sc[64], sh[64];
    const int t = threadIdx.x;
    if (blockIdx.x < 64 && t < 128) ws[G_ST2 + (size_t)blockIdx.x * 128 + t] = 0.f;
    if (t < 64) {
        float S = 0.f, Q = 0.f;
        for (int s = 0; s < 256; ++s) {
            S += ws[G_BN1 + (size_t)s * 128 + t];
            Q += ws[G_BN1 + (size_t)s * 128 + 64 + t];
        }
        float inv = 1.f / (float)NETOT;
        float mean = S * inv, var = Q * inv - mean * mean;
        float s_ = g[t] * rsqrtf(var + EPS);
        sc[t] = s_;
        sh[t] = be[t] - mean * s_;
    }
    __syncthreads();
    size_t gid = (size_t)blockIdx.x * 256 + t;      // 480*256 = ROWS*64/8
    size_t base = gid * 8;
    int k0 = (int)(gid & 7) << 3;
    float4 u0 = *reinterpret_cast<const float4*>(ws + F_U + base);
    float4 u1 = *reinterpret_cast<const float4*>(ws + F_U + base + 4);
    float4 v0 = *reinterpret_cast<const float4*>(ws + F_V + base);
    float4 v1 = *reinterpret_cast<const float4*>(ws + F_V + base + 4);
    uint4 ou, ov;
    ou.x = cvtpk16(sc[k0+0]*u0.x + sh[k0+0], sc[k0+1]*u0.y + sh[k0+1]);
    ou.y = cvtpk16(sc[k0+2]*u0.z + sh[k0+2], sc[k0+3]*u0.w + sh[k0+3]);
    ou.z = cvtpk16(sc[k0+4]*u1.x + sh[k0+4], sc[k0+5]*u1.y + sh[k0+5]);
    ou.w = cvtpk16(sc[k0+6]*u1.z + sh[k0+6], sc[k0+7]*u1.w + sh[k0+7]);
    ov.x = cvtpk16(sc[k0+0]*v0.x, sc[k0+1]*v0.y);
    ov.y = cvtpk16(sc[k0+2]*v0.z, sc[k0+3]*v0.w);
    ov.z = cvtpk16(sc[k0+4]*v1.x, sc[k0+5]*v1.y);
    ov.w = cvtpk16(sc[k0+6]*v1.z, sc[k0+7]*v1.w);
    reinterpret_cast<uint4*>(ws + F_UH)[gid] = ou;
    reinterpret_cast<uint4*>(ws + F_VH)[gid] = ov;
}

// ---- KEDGE<STAGE>: 4 blocks/batch, 15 groups each, 1 group per wave, barrier-free ----
// STAGE1: h2 raw stats -> G_ST2 (zeroes G_ST3).
// STAGE2: e2 = relu(bn2(h2)); h3 = e2*W3^T; STORE h3 fp16; raw h3 stats -> G_ST3 (zeroes G_SO1).
template <int STAGE>
__global__ __launch_bounds__(256, 4) void kedge(
    const float* __restrict__ fr2_w, const float* __restrict__ fr3_w,
    const float* __restrict__ g2, const float* __restrict__ be2,
    float* __restrict__ ws)
{
    __shared__ __align__(16) ushortT sUVh[75 * 72];   // rows 0..59 V', 60..74 U'
    __shared__ __align__(16) ushortT scrAll[4 * 1024];
    __shared__ float sBN[128];
    __shared__ float red[128];

    const int blk = blockIdx.x;
    const int b = blk >> 2, q = blk & 3;
    const int t = threadIdx.x;
    const int wv = t >> 6, lane = t & 63;
    const int gq = lane >> 4, ln = lane & 15;
    const f32x4 zero = {0.f, 0.f, 0.f, 0.f};

    if constexpr (STAGE == 1) {
        if (blk < 64 && t < 64) ws[G_ST3 + (size_t)blk * 64 + t] = 0.f;
    } else {
        if (blk < 16 && t < 128) ws[G_SO1 + (size_t)blk * 128 + t] = 0.f;
    }

    {
        const ushortT* vh = reinterpret_cast<const ushortT*>(ws + F_VH) + (size_t)b * N_ * 64;
        const ushortT* uh = reinterpret_cast<const ushortT*>(ws + F_UH) + (size_t)(b * N_ + q * 15) * 64;
        for (int idx = t; idx < 480; idx += 256) {
            int r = idx >> 3, c = (idx & 7) << 3;
            *reinterpret_cast<uint4*>(&sUVh[r * 72 + c]) =
                *reinterpret_cast<const uint4*>(&vh[(size_t)r * 64 + c]);
        }
        if (t < 120) {
            int r = t >> 3, c = (t & 7) << 3;
            *reinterpret_cast<uint4*>(&sUVh[(60 + r) * 72 + c]) =
                *reinterpret_cast<const uint4*>(&uh[(size_t)r * 64 + c]);
        }
    }
    if constexpr (STAGE == 2) {
        if (t < 64) {
            float S = 0.f, Q = 0.f;
            for (int s = 0; s < 64; ++s) {
                S += ws[G_ST2 + (size_t)s * 128 + t];
                Q += ws[G_ST2 + (size_t)s * 128 + 64 + t];
            }
            float inv = 1.f / (float)NETOT;
            float m = S * inv, var = Q * inv - m * m;
            float s_ = g2[t] * rsqrtf(var + EPS);
            sBN[t] = s_; sBN[64 + t] = be2[t] - m * s_;
        }
    }
    if (t < 128) red[t] = 0.f;

    // weight fragments -> registers (inline f32 -> fp16 conversion)
    f16x8 w2f0[4], w2f1[4], w3f0[2], w3f1[2];
    #pragma unroll
    for (int mu = 0; mu < 4; ++mu) {
        w2f0[mu] = ldf16(fr2_w + (size_t)(mu * 16 + ln) * 64 + gq * 8);
        w2f1[mu] = ldf16(fr2_w + (size_t)(mu * 16 + ln) * 64 + 32 + gq * 8);
    }
    if constexpr (STAGE == 2) {
        #pragma unroll
        for (int nv = 0; nv < 2; ++nv) {
            w3f0[nv] = ldf16(fr3_w + (size_t)(nv * 16 + ln) * 64 + gq * 8);
            w3f1[nv] = ldf16(fr3_w + (size_t)(nv * 16 + ln) * 64 + 32 + gq * 8);
        }
    }
    __syncthreads();

    ushortT* scr = scrAll + wv * 1024;

    if constexpr (STAGE == 1) {
        f32x4 s1s[4] = {zero, zero, zero, zero};
        f32x4 s1q[4] = {zero, zero, zero, zero};
        for (int gi = wv; gi < 15; gi += 4) {
            const int i = q * 15 + gi;
            uint4 uu0 = *reinterpret_cast<const uint4*>(&sUVh[(60 + gi) * 72 + gq * 8]);
            uint4 uu1 = *reinterpret_cast<const uint4*>(&sUVh[(60 + gi) * 72 + 32 + gq * 8]);
            #pragma unroll
            for (int m = 0; m < 4; ++m) {
                int e = (m << 4) + ln;
                int j = e + (e >= i ? 1 : 0);
                uint4 vv0 = *reinterpret_cast<const uint4*>(&sUVh[j * 72 + gq * 8]);
                uint4 vv1 = *reinterpret_cast<const uint4*>(&sUVh[j * 72 + 32 + gq * 8]);
                f16x8 ef0 = erelu(uu0, vv0, e < 59);
                f16x8 ef1 = erelu(uu1, vv1, e < 59);
                #pragma unroll
                for (int mu = 0; mu < 4; ++mu) {
                    f32x4 acc = __builtin_amdgcn_mfma_f32_16x16x32_f16(w2f0[mu], ef0, zero, 0, 0, 0);
                    acc = __builtin_amdgcn_mfma_f32_16x16x32_f16(w2f1[mu], ef1, acc, 0, 0, 0);
                    s1s[mu] += acc;
                    s1q[mu] += acc * acc;
                }
            }
        }
        #pragma unroll
        for (int off = 1; off <= 8; off <<= 1)
            #pragma unroll
            for (int mu = 0; mu < 4; ++mu)
                #pragma unroll
                for (int r = 0; r < 4; ++r) {
                    s1s[mu][r] += __shfl_xor(s1s[mu][r], off);
                    s1q[mu][r] += __shfl_xor(s1q[mu][r], off);
                }
        if (ln == 0) {
            #pragma unroll
            for (int mu = 0; mu < 4; ++mu)
                #pragma unroll
                for (int r = 0; r < 4; ++r) {
                    atomicAdd(&red[mu * 16 + gq * 4 + r], s1s[mu][r]);
                    atomicAdd(&red[64 + mu * 16 + gq * 4 + r], s1q[mu][r]);
                }
        }
        __syncthreads();
        if (t < 128) atomicAdd(ws + G_ST2 + (size_t)(blk & 63) * 128 + t, red[t]);
    } else {
        float st0 = 0.f, st1 = 0.f, st2 = 0.f, st3 = 0.f;
        ushortT* __restrict__ h3p = reinterpret_cast<ushortT*>(ws + F_H3);
        for (int gi = wv; gi < 15; gi += 4) {
            const int i = q * 15 + gi;
            const size_t ebase = ((size_t)b * NE + (size_t)i * 59) * 32;
            uint4 uu0 = *reinterpret_cast<const uint4*>(&sUVh[(60 + gi) * 72 + gq * 8]);
            uint4 uu1 = *reinterpret_cast<const uint4*>(&sUVh[(60 + gi) * 72 + 32 + gq * 8]);
            #pragma unroll
            for (int m = 0; m < 4; ++m) {
                int e = (m << 4) + ln;
                int j = e + (e >= i ? 1 : 0);
                uint4 vv0 = *reinterpret_cast<const uint4*>(&sUVh[j * 72 + gq * 8]);
                uint4 vv1 = *reinterpret_cast<const uint4*>(&sUVh[j * 72 + 32 + gq * 8]);
                const bool eok = e < 59;
                f16x8 ef0 = erelu(uu0, vv0, eok);
                f16x8 ef1 = erelu(uu1, vv1, eok);
                f32x4 ac[4];
                #pragma unroll
                for (int mu = 0; mu < 4; ++mu) {
                    ac[mu] = __builtin_amdgcn_mfma_f32_16x16x32_f16(w2f0[mu], ef0, zero, 0, 0, 0);
                    ac[mu] = __builtin_amdgcn_mfma_f32_16x16x32_f16(w2f1[mu], ef1, ac[mu], 0, 0, 0);
                }
                // e2 = relu(bn2(h2)) -> per-wave LDS transpose scatter (verified mapping)
                #pragma unroll
                for (int mu = 0; mu < 4; ++mu) {
                    int fb = mu * 16 + (gq << 2);
                    float4 sc2 = *reinterpret_cast<const float4*>(sBN + fb);
                    float4 sh2 = *reinterpret_cast<const float4*>(sBN + 64 + fb);
                    unsigned int pk0 = cvtpk16(fmaxf(0.f, sc2.x * ac[mu][0] + sh2.x),
                                               fmaxf(0.f, sc2.y * ac[mu][1] + sh2.y));
                    unsigned int pk1 = cvtpk16(fmaxf(0.f, sc2.z * ac[mu][2] + sh2.z),
                                               fmaxf(0.f, sc2.w * ac[mu][3] + sh2.w));
                    if (!eok) { pk0 = 0u; pk1 = 0u; }
                    int lp = ln + ((((mu << 1) + (gq >> 1)) & 3) << 4);
                    int off = ((mu >> 1) << 9) + (lp << 3) + ((gq & 1) << 2);
                    uint2 pr; pr.x = pk0; pr.y = pk1;
                    *reinterpret_cast<uint2*>(&scr[off]) = pr;
                }
                __threadfence_block();
                union { uint4 q4; f16x8 v; } ea0, ea1;
                ea0.q4 = *reinterpret_cast<const uint4*>(&scr[lane << 3]);
                ea1.q4 = *reinterpret_cast<const uint4*>(&scr[512 + (lane << 3)]);
                f32x4 a30 = __builtin_amdgcn_mfma_f32_16x16x32_f16(ea0.v, w3f0[0], zero, 0, 0, 0);
                a30 = __builtin_amdgcn_mfma_f32_16x16x32_f16(ea1.v, w3f1[0], a30, 0, 0, 0);
                f32x4 a31 = __builtin_amdgcn_mfma_f32_16x16x32_f16(ea0.v, w3f0[1], zero, 0, 0, 0);
                a31 = __builtin_amdgcn_mfma_f32_16x16x32_f16(ea1.v, w3f1[1], a31, 0, 0, 0);
                // stats (pads contribute exact zeros) + h3 store (C/D: row e = m*16+gq*4+r, col f = nv*16+ln)
                #pragma unroll
                for (int r = 0; r < 4; ++r) {
                    st0 += a30[r]; st1 += a30[r] * a30[r];
                    st2 += a31[r]; st3 += a31[r] * a31[r];
                    int el = (m << 4) + (gq << 2) + r;
                    if (el < 59) {
                        size_t rb = ebase + (size_t)el * 32;
                        h3p[rb + ln] = (ushortT)(cvtpk16(a30[r], 0.f) & 0xffffu);
                        h3p[rb + 16 + ln] = (ushortT)(cvtpk16(a31[r], 0.f) & 0xffffu);
                    }
                }
            }
        }
        st0 += __shfl_xor(st0, 16); st0 += __shfl_xor(st0, 32);
        st1 += __shfl_xor(st1, 16); st1 += __shfl_xor(st1, 32);
        st2 += __shfl_xor(st2, 16); st2 += __shfl_xor(st2, 32);
        st3 += __shfl_xor(st3, 16); st3 += __shfl_xor(st3, 32);
        if (lane < 16) {
            atomicAdd(&red[ln], st0);      atomicAdd(&red[16 + ln], st2);
            atomicAdd(&red[32 + ln], st1); atomicAdd(&red[48 + ln], st3);
        }
        __syncthreads();
        if (t < 64) atomicAdd(ws + G_ST3 + (size_t)(blk & 63) * 64 + t, red[t]);
    }
}

// ---- K8: stream h3; inline bn3 finalize; relu; segment-sum -> EBAR; zero G_SO2 ----
__global__ __launch_bounds__(256) void k8_scatter(const float* __restrict__ g3,
                                                  const float* __restrict__ be3,
                                                  float* __restrict__ ws) {
    __shared__ float sc3[32], sh3[32];
    const int t = threadIdx.x;
    if ((int)blockIdx.x < 16 && t < 128)
        ws[G_SO2 + (size_t)blockIdx.x * 128 + t] = 0.f;
    if (t < 32) {
        float S = 0.f, Q = 0.f;
        for (int s = 0; s < 64; ++s) {
            S += ws[G_ST3 + (size_t)s * 64 + t];
            Q += ws[G_ST3 + (size_t)s * 64 + 32 + t];
        }
        float inv = 1.f / (float)NETOT;
        float m = S * inv, var = Q * inv - m * m;
        float sc = g3[t] * rsqrtf(var + EPS);
        sc3[t] = sc; sh3[t] = be3[t] - m * sc;
    }
    __syncthreads();
    const int wv = t >> 6, lane = t & 63;
    const int fp = lane & 15, h = lane >> 4;       // f pair index, row phase
    const int grp = blockIdx.x * 4 + wv;           // (b,i) group
    const int b = grp / N_, i = grp - b * N_;
    const unsigned int* __restrict__ h3u =
        reinterpret_cast<const unsigned int*>(ws + F_H3) + ((size_t)b * NE + (size_t)i * 59) * 16;
    const int f0 = fp * 2;
    const float s0 = sc3[f0], s1 = sc3[f0 + 1];
    const float t0 = sh3[f0], t1 = sh3[f0 + 1];
    float a0 = 0.f, a1 = 0.f;
    for (int r = h; r < 59; r += 4) {
        union { unsigned int u; __fp16 hh[2]; } v;
        v.u = h3u[(size_t)r * 16 + fp];
        a0 += fmaxf(0.f, s0 * (float)v.hh[0] + t0);
        a1 += fmaxf(0.f, s1 * (float)v.hh[1] + t1);
    }
    a0 += __shfl_xor(a0, 16); a0 += __shfl_xor(a0, 32);
    a1 += __shfl_xor(a1, 16); a1 += __shfl_xor(a1, 32);
    if (h == 0) {
        float2 r2; r2.x = a0; r2.y = a1;
        *reinterpret_cast<float2*>(ws + F_EBAR + (size_t)grp * 32 + f0) = r2;
    }
}

// ---- object-path linear; optional inline BN finalize (16-slot sum); slotted output stats ----
template <int OUT, int FIN>
__global__ __launch_bounds__(256) void kobj(const float* __restrict__ srcA,
                                            const float* __restrict__ srcB,
                                            const float* __restrict__ statIn,
                                            const float* __restrict__ gP,
                                            const float* __restrict__ beP,
                                            const float* __restrict__ W,
                                            float* __restrict__ outp,
                                            float* __restrict__ statOut,
                                            float* __restrict__ zeroPtr,
                                            int zeroCnt) {
    constexpr int TRN = (OUT == 64) ? 16 : 32;
    constexpr int RB = 4 * TRN;
    constexpr int SP = RB + 4;
    constexpr int WP = OUT + 4;
    __shared__ __align__(16) float sinT[64 * SP];
    __shared__ __align__(16) float swt[64 * WP];
    __shared__ float sAct[128];
    const int t = threadIdx.x;
    const int row0 = blockIdx.x * RB;
    if (zeroPtr && (int)blockIdx.x < 16 && t < zeroCnt)
        zeroPtr[(size_t)blockIdx.x * zeroCnt + t] = 0.f;
    if (FIN > 0 && t < 64) {
        float S = 0.f, Q = 0.f;
        #pragma unroll
        for (int s = 0; s < 16; ++s) {
            S += statIn[(size_t)s * 128 + t];
            Q += statIn[(size_t)s * 128 + 64 + t];
        }
        float inv = 1.f / (float)ROWS;
        float m = S * inv, var = Q * inv - m * m;
        float sc = gP[t] * rsqrtf(var + EPS);
        sAct[t] = sc; sAct[64 + t] = beP[t] - m * sc;
    }
    __syncthreads();
    for (int idx = t; idx < RB * 64; idx += 256) {
        int r = idx % RB, k = idx / RB;
        float v;
        if (srcB) {
            v = (k < 32) ? srcA[(size_t)(row0 + r) * 32 + k]
                         : srcB[(size_t)(row0 + r) * 32 + (k - 32)];
        } else {
            v = srcA[(size_t)(row0 + r) * 64 + k];
        }
        if (FIN > 0) v = fmaxf(0.f, sAct[k] * v + sAct[64 + k]);
        sinT[k * SP + r] = v;
    }
    for (int idx = t; idx < OUT * 64; idx += 256) {
        int o = idx >> 6, k = idx & 63;
        swt[k * WP + o] = W[idx];
    }
    __syncthreads();
    const int tr = t % TRN, to = t / TRN;
    const int r0 = tr * 4, o0 = to * 4;
    float acc[4][4];
    #pragma unroll
    for (int a = 0; a < 4; ++a)
        #pragma unroll
        for (int c = 0; c < 4; ++c) acc[a][c] = 0.f;
    #pragma unroll 8
    for (int k = 0; k < 64; ++k) {
        float4 a4 = *reinterpret_cast<const float4*>(sinT + k * SP + r0);
        float4 w4 = *reinterpret_cast<const float4*>(swt + k * WP + o0);
        float av[4] = {a4.x, a4.y, a4.z, a4.w};
        float wv[4] = {w4.x, w4.y, w4.z, w4.w};
        #pragma unroll
        for (int a = 0; a < 4; ++a)
            #pragma unroll
            for (int c = 0; c < 4; ++c) acc[a][c] += av[a] * wv[c];
    }
    float lsum[4] = {0.f, 0.f, 0.f, 0.f}, lsq[4] = {0.f, 0.f, 0.f, 0.f};
    #pragma unroll
    for (int a = 0; a < 4; ++a) {
        float4 res;
        res.x = acc[a][0]; res.y = acc[a][1]; res.z = acc[a][2]; res.w = acc[a][3];
        #pragma unroll
        for (int c = 0; c < 4; ++c) { lsum[c] += acc[a][c]; lsq[c] += acc[a][c] * acc[a][c]; }
        *reinterpret_cast<float4*>(outp + (size_t)(row0 + r0 + a) * OUT + o0) = res;
    }
    #pragma unroll
    for (int o = TRN / 2; o >= 1; o >>= 1) {
        #pragma unroll
        for (int c = 0; c < 4; ++c) {
            lsum[c] += __shfl_down(lsum[c], o, TRN);
            lsq[c]  += __shfl_down(lsq[c], o, TRN);
        }
    }
    if (tr == 0) {
        float* so = statOut + (size_t)(blockIdx.x & 15) * (2 * OUT);
        #pragma unroll
        for (int c = 0; c < 4; ++c) {
            atomicAdd(so + o0 + c, lsum[c]);
            atomicAdd(so + OUT + o0 + c, lsq[c]);
        }
    }
}

// ---- K15: inline fin3 (16-slot sum); relu(bn(ho3)); pool; fc ----
__global__ __launch_bounds__(64) void k15_final(const float* __restrict__ g,
                                                const float* __restrict__ be,
                                                const float* __restrict__ fcw,
                                                const float* __restrict__ fcb,
                                                float* __restrict__ ws,
                                                float* __restrict__ out) {
    __shared__ float sc3s[32], sh3s[32];
    int b = blockIdx.x, t = threadIdx.x;
    if (t < 32) {
        float S = 0.f, Q = 0.f;
        #pragma unroll
        for (int s = 0; s < 16; ++s) {
            S += ws[G_SO3 + (size_t)s * 64 + t];
            Q += ws[G_SO3 + (size_t)s * 64 + 32 + t];
        }
        float inv = 1.f / (float)ROWS;
        float m = S * inv, var = Q * inv - m * m;
        float sc = g[t] * rsqrtf(var + EPS);
        sc3s[t] = sc; sh3s[t] = be[t] - m * sc;
    }
    __syncthreads();
    int f = t & 31, h = t >> 5;
    float sc = sc3s[f], sh = sh3s[f];
    float acc = 0.f;
    for (int n = h; n < N_; n += 2) {
        float v = ws[F_HO3 + (size_t)(b * N_ + n) * 32 + f];
        acc += fmaxf(0.f, sc * v + sh);
    }
    acc += __shfl_down(acc, 32);
    float p0 = acc * fcw[f];
    float p1 = acc * fcw[32 + f];
    #pragma unroll
    for (int o = 16; o >= 1; o >>= 1) {
        p0 += __shfl_xor(p0, o);
        p1 += __shfl_xor(p1, o);
    }
    if (t == 0) {
        out[b * 2 + 0] = p0 + fcb[0];
        out[b * 2 + 1] = p1 + fcb[1];
    }
}

extern "C" void kernel_launch(void* const* d_in, const int* in_sizes, int n_in,
                              void* d_out, int out_size, void* d_ws, size_t ws_size,
                              hipStream_t stream) {
    const float* x      = (const float*)d_in[0];
    const float* bnx_g  = (const float*)d_in[1];
    const float* bnx_b  = (const float*)d_in[2];
    const float* fr1_w  = (const float*)d_in[3];
    const float* fr1_g  = (const float*)d_in[5];
    const float* fr1_be = (const float*)d_in[6];
    const float* fr2_w  = (const float*)d_in[7];
    const float* fr2_g  = (const float*)d_in[9];
    const float* fr2_be = (const float*)d_in[10];
    const float* fr3_w  = (const float*)d_in[11];
    const float* fr3_g  = (const float*)d_in[13];
    const float* fr3_be = (const float*)d_in[14];
    const float* fo1_w  = (const float*)d_in[15];
    const float* fo1_g  = (const float*)d_in[17];
    const float* fo1_be = (const float*)d_in[18];
    const float* fo2_w  = (const float*)d_in[19];
    const float* fo2_g  = (const float*)d_in[21];
    const float* fo2_be = (const float*)d_in[22];
    const float* fo3_w  = (const float*)d_in[23];
    const float* fo3_g  = (const float*)d_in[25];
    const float* fo3_be = (const float*)d_in[26];
    const float* fc_w   = (const float*)d_in[27];
    const float* fc_b   = (const float*)d_in[28];

    float* ws = (float*)d_ws;
    float* out = (float*)d_out;
    if (ws_size < F_TOTAL * sizeof(float)) return;

    k0_part<<<256, 256, 0, stream>>>(x, ws);
    k1_uv<<<B_, 256, 0, stream>>>(x, fr1_w, bnx_g, bnx_b, ws);
    k3b<<<480, 256, 0, stream>>>(fr1_g, fr1_be, ws);
    kedge<1><<<B_ * 4, 256, 0, stream>>>(fr2_w, fr3_w, fr2_g, fr2_be, ws);
    kedge<2><<<B_ * 4, 256, 0, stream>>>(fr2_w, fr3_w, fr2_g, fr2_be, ws);
    k8_scatter<<<ROWS / 4, 256, 0, stream>>>(fr3_g, fr3_be, ws);
    kobj<64, 0><<<ROWS / 64, 256, 0, stream>>>(ws + F_XT, ws + F_EBAR, nullptr, nullptr, nullptr,
                                               fo1_w, ws + F_HO1, ws + G_SO1, ws + G_SO3, 64);
    kobj<64, 64><<<ROWS / 64, 256, 0, stream>>>(ws + F_HO1, nullptr, ws + G_SO1, fo1_g, fo1_be,
                                                fo2_w, ws + F_HO2, ws + G_SO2, nullptr, 0);
    kobj<32, 64><<<ROWS / 128, 256, 0, stream>>>(ws + F_HO2, nullptr, ws + G_SO2, fo2_g, fo2_be,
                                                 fo3_w, ws + F_HO3, ws + G_SO3, nullptr, 0);
    k15_final<<<B_, 64, 0, stream>>>(fo3_g, fo3_be, fc_w, fc_b, ws, out);
}

// Round 14
// 142.466 us; speedup vs baseline: 1.0208x; 1.0019x over previous
//
#include <hip/hip_runtime.h>

typedef unsigned short ushortT;
typedef _Float16 f16x8 __attribute__((ext_vector_type(8)));
typedef __fp16 fp16v2 __attribute__((ext_vector_type(2)));
typedef __attribute__((ext_vector_type(4))) float f32x4;

constexpr int B_ = 256, P_ = 32, N_ = 60;
constexpr int NE = N_ * (N_ - 1);          // 3540
constexpr int NETOT = B_ * NE;             // 906240
constexpr int ROWS = B_ * N_;              // 15360
constexpr float EPS = 1e-5f;

// ---- workspace layout (float offsets) ----
constexpr size_t F_XT  = 0;                          // ROWS*32
constexpr size_t F_EBAR = F_XT + (size_t)ROWS * 32;  // ROWS*32
constexpr size_t F_HO1 = F_EBAR + (size_t)ROWS * 32; // ROWS*64
constexpr size_t F_HO2 = F_HO1 + (size_t)ROWS * 64;  // ROWS*64
constexpr size_t F_HO3 = F_HO2 + (size_t)ROWS * 64;  // ROWS*32
constexpr size_t F_U   = F_HO3 + (size_t)ROWS * 32;  // ROWS*64 f32 (raw, no b1)
constexpr size_t F_V   = F_U + (size_t)ROWS * 64;    // ROWS*64 f32
constexpr size_t F_UH  = F_V + (size_t)ROWS * 64;    // ROWS*64 fp16 packed
constexpr size_t F_VH  = F_UH + (size_t)ROWS * 32;   // ROWS*64 fp16 packed
constexpr size_t F_H3  = F_VH + (size_t)ROWS * 32;   // NETOT*32 fp16 = NETOT*16 floats
// stat accumulators: NO host memset. Direct-store slots where block->slot is
// unique; atomic slots are zeroed by a PRECEDING kernel in the chain.
constexpr size_t G_B   = F_H3 + (size_t)NETOT * 16;
constexpr size_t G_INS = G_B;                  // 8 slots x 64   (direct store: k0)
constexpr size_t G_BN1 = G_INS + 8 * 64;       // 256 slots x 128 (direct store: k1)
constexpr size_t G_ST2 = G_BN1 + 256 * 128;    // 64 slots x 128 (atomic; zeroed in k3b)
constexpr size_t G_ST3 = G_ST2 + 64 * 128;     // 64 slots x 64  (atomic; zeroed in kedge1)
constexpr size_t G_SO1 = G_ST3 + 64 * 64;      // 16 slots x 128 (atomic; zeroed in kedge2)
constexpr size_t G_SO2 = G_SO1 + 16 * 128;     // 16 slots x 128 (atomic; zeroed in k8)
constexpr size_t G_SO3 = G_SO2 + 16 * 128;     // 16 slots x 64  (atomic; zeroed in kobj1)
constexpr size_t G_CNT = 8 * 64 + 256 * 128 + 64 * 128 + 64 * 64 + 16 * 128 + 16 * 128 + 16 * 64;
constexpr size_t F_TOTAL = G_B + G_CNT;

static __device__ __forceinline__ unsigned int cvtpk16(float lo, float hi) {
    union { fp16v2 h; unsigned int u; } r;
    r.h = __builtin_amdgcn_cvt_pkrtz(lo, hi);
    return r.u;
}
static __device__ __forceinline__ unsigned int hadd_relu(unsigned int a, unsigned int b) {
    unsigned int r;
    asm("v_pk_add_f16 %0, %1, %2\n\tv_pk_max_f16 %0, %0, 0"
        : "=v"(r) : "v"(a), "v"(b));
    return r;
}
static __device__ __forceinline__ f16x8 ldf16(const float* __restrict__ p) {
    float4 a = *reinterpret_cast<const float4*>(p);
    float4 b = *reinterpret_cast<const float4*>(p + 4);
    union { unsigned int u[4]; f16x8 v; } r;
    r.u[0] = cvtpk16(a.x, a.y); r.u[1] = cvtpk16(a.z, a.w);
    r.u[2] = cvtpk16(b.x, b.y); r.u[3] = cvtpk16(b.z, b.w);
    return r.v;
}
static __device__ __forceinline__ f16x8 erelu(uint4 uu, uint4 vv, bool ok) {
    union { unsigned int u[4]; f16x8 v; } r;
    r.u[0] = hadd_relu(uu.x, vv.x);
    r.u[1] = hadd_relu(uu.y, vv.y);
    r.u[2] = hadd_relu(uu.z, vv.z);
    r.u[3] = hadd_relu(uu.w, vv.w);
    if (!ok) { r.u[0] = 0u; r.u[1] = 0u; r.u[2] = 0u; r.u[3] = 0u; }
    return r.v;
}

// ---- K0: input BN raw stats (direct store, unique (seg,p) slot) ----
__global__ __launch_bounds__(256) void k0_part(const float* __restrict__ x,
                                               float* __restrict__ ws) {
    int p = blockIdx.x & 31, seg = blockIdx.x >> 5;
    float s = 0.f, q = 0.f;
    for (int idx = threadIdx.x; idx < 32 * N_; idx += 256) {
        int bb = seg * 32 + idx / N_;
        int n = idx - (idx / N_) * N_;
        float v = x[(size_t)(bb * P_ + p) * N_ + n];
        s += v; q += v * v;
    }
    for (int o = 32; o > 0; o >>= 1) { s += __shfl_down(s, o); q += __shfl_down(q, o); }
    __shared__ float rs[4], rq[4];
    int wid = threadIdx.x >> 6, lane = threadIdx.x & 63;
    if (lane == 0) { rs[wid] = s; rq[wid] = q; }
    __syncthreads();
    if (threadIdx.x == 0) {
        s = rs[0] + rs[1] + rs[2] + rs[3];
        q = rq[0] + rq[1] + rq[2] + rq[3];
        float* slot = ws + G_INS + (size_t)seg * 64;
        slot[p] = s;
        slot[32 + p] = q;
    }
}

// ---- K1: inline input-BN finalize (8-slot sum); U,V raw; xt; BN1 partial direct-store ----
__global__ __launch_bounds__(256) void k1_uv(const float* __restrict__ x,
                                             const float* __restrict__ w1,
                                             const float* __restrict__ bnx_g,
                                             const float* __restrict__ bnx_b,
                                             float* __restrict__ ws) {
    int b = blockIdx.x;
    __shared__ float xs[P_ * N_];
    __shared__ float w1t[64 * 65];
    __shared__ float sX[32], tX[32];
    __shared__ float rbn[4][5][64];
    const int t = threadIdx.x;
    if (t < 32) {
        float S = 0.f, Q = 0.f;
        #pragma unroll
        for (int s = 0; s < 8; ++s) {
            S += ws[G_INS + (size_t)s * 64 + t];
            Q += ws[G_INS + (size_t)s * 64 + 32 + t];
        }
        float inv = 1.f / (float)(B_ * N_);
        float mean = S * inv;
        float var = Q * inv - mean * mean;
        float sc = bnx_g[t] * rsqrtf(var + EPS);
        sX[t] = sc;
        tX[t] = bnx_b[t] - mean * sc;
    }
    for (int idx = t; idx < 64 * 64; idx += 256) {
        int k = idx >> 6, c = idx & 63;
        w1t[c * 65 + k] = w1[idx];
    }
    __syncthreads();
    for (int idx = t; idx < P_ * N_; idx += 256) {
        int p = idx / N_, n = idx - (idx / N_) * N_;
        xs[idx] = sX[p] * x[(size_t)(b * P_ + p) * N_ + n] + tX[p];
    }
    __syncthreads();
    for (int idx = t; idx < N_ * P_; idx += 256) {
        int n = idx / P_, p = idx - (idx / P_) * P_;
        ws[F_XT + (size_t)(b * N_ + n) * P_ + p] = xs[p * N_ + n];
    }
    const int k = t & 63, ph = t >> 6;
    float wu[32], wv[32];
    #pragma unroll
    for (int p = 0; p < 32; ++p) {
        wu[p] = w1t[p * 65 + k];
        wv[p] = w1t[(32 + p) * 65 + k];
    }
    float su = 0, sv = 0, suu = 0, svv = 0, suv = 0;
    for (int idx = t; idx < N_ * 64; idx += 256) {
        int n = idx >> 6;
        float u = 0.f, v = 0.f;
        #pragma unroll
        for (int p = 0; p < 32; ++p) {
            float xv = xs[p * N_ + n];
            u += xv * wu[p];
            v += xv * wv[p];
        }
        ws[F_U + (size_t)(b * N_ + n) * 64 + k] = u;
        ws[F_V + (size_t)(b * N_ + n) * 64 + k] = v;
        su += u; sv += v; suu += u * u; svv += v * v; suv += u * v;
    }
    rbn[ph][0][k] = su; rbn[ph][1][k] = sv; rbn[ph][2][k] = suu;
    rbn[ph][3][k] = svv; rbn[ph][4][k] = suv;
    __syncthreads();
    if (t < 64) {
        float S_u = 0, S_v = 0, Quu = 0, Qvv = 0, Quv = 0;
        #pragma unroll
        for (int p2 = 0; p2 < 4; ++p2) {
            S_u += rbn[p2][0][t]; S_v += rbn[p2][1][t]; Quu += rbn[p2][2][t];
            Qvv += rbn[p2][3][t]; Quv += rbn[p2][4][t];
        }
        float* slot = ws + G_BN1 + (size_t)b * 128;   // unique slot per block
        slot[t] = 59.f * (S_u + S_v);
        slot[64 + t] = 59.f * (Quu + Qvv) + 2.f * (S_u * S_v - Quv);
    }
}

// ---- K3b: inline BN1 finalize (256-slot sum); fold & convert U,V -> fp16; zero G_ST2 ----
__global__ __launch_bounds__(256) void k3b(const float* __restrict__ g,
                                           const float* __restrict__ be,
                                           float* __restrict__ ws) {
    __shared__ float sc[64], sh[64];
    const int t = threadIdx.x;
    if (blockIdx.x < 64 && t < 128) ws[G_ST2 + (size_t)blockIdx.x * 128 + t] = 0.f;
    if (t < 64) {
        float S = 0.f, Q = 0.f;
        for (int s = 0; s < 256; ++s) {
            S += ws[G_BN1 + (size_t)s * 128 + t];
            Q += ws[G_BN1 + (size_t)s * 128 + 64 + t];
        }
        float inv = 1.f / (float)NETOT;
        float mean = S * inv, var = Q * inv - mean * mean;
        float s_ = g[t] * rsqrtf(var + EPS);
        sc[t] = s_;
        sh[t] = be[t] - mean * s_;
    }
    __syncthreads();
    size_t gid = (size_t)blockIdx.x * 256 + t;      // 480*256 = ROWS*64/8
    size_t base = gid * 8;
    int k0 = (int)(gid & 7) << 3;
    float4 u0 = *reinterpret_cast<const float4*>(ws + F_U + base);
    float4 u1 = *reinterpret_cast<const float4*>(ws + F_U + base + 4);
    float4 v0 = *reinterpret_cast<const float4*>(ws + F_V + base);
    float4 v1 = *reinterpret_cast<const float4*>(ws + F_V + base + 4);
    uint4 ou, ov;
    ou.x = cvtpk16(sc[k0+0]*u0.x + sh[k0+0], sc[k0+1]*u0.y + sh[k0+1]);
    ou.y = cvtpk16(sc[k0+2]*u0.z + sh[k0+2], sc[k0+3]*u0.w + sh[k0+3]);
    ou.z = cvtpk16(sc[k0+4]*u1.x + sh[k0+4], sc[k0+5]*u1.y + sh[k0+5]);
    ou.w = cvtpk16(sc[k0+6]*u1.z + sh[k0+6], sc[k0+7]*u1.w + sh[k0+7]);
    ov.x = cvtpk16(sc[k0+0]*v0.x, sc[k0+1]*v0.y);
    ov.y = cvtpk16(sc[k0+2]*v0.z, sc[k0+3]*v0.w);
    ov.z = cvtpk16(sc[k0+4]*v1.x, sc[k0+5]*v1.y);
    ov.w = cvtpk16(sc[k0+6]*v1.z, sc[k0+7]*v1.w);
    reinterpret_cast<uint4*>(ws + F_UH)[gid] = ou;
    reinterpret_cast<uint4*>(ws + F_VH)[gid] = ov;
}

// ---- KEDGE<STAGE>: 4 blocks/batch, 15 groups each, 1 group per wave, barrier-free ----
// STAGE1: h2 raw stats -> G_ST2 (zeroes G_ST3).
// STAGE2: e2 = relu(bn2(h2)); h3 = e2*W3^T (2-deep m-pipelined); STORE h3 fp16;
//         raw h3 stats -> G_ST3 (zeroes G_SO1).
template <int STAGE>
__global__ __launch_bounds__(256, 4) void kedge(
    const float* __restrict__ fr2_w, const float* __restrict__ fr3_w,
    const float* __restrict__ g2, const float* __restrict__ be2,
    float* __restrict__ ws)
{
    __shared__ __align__(16) ushortT sUVh[75 * 72];   // rows 0..59 V', 60..74 U'
    __shared__ __align__(16) ushortT scrAll[(STAGE == 2) ? 8 * 1024 : 16];
    __shared__ float sBN[128];
    __shared__ float red[128];

    const int blk = blockIdx.x;
    const int b = blk >> 2, q = blk & 3;
    const int t = threadIdx.x;
    const int wv = t >> 6, lane = t & 63;
    const int gq = lane >> 4, ln = lane & 15;
    const f32x4 zero = {0.f, 0.f, 0.f, 0.f};

    if constexpr (STAGE == 1) {
        if (blk < 64 && t < 64) ws[G_ST3 + (size_t)blk * 64 + t] = 0.f;
    } else {
        if (blk < 16 && t < 128) ws[G_SO1 + (size_t)blk * 128 + t] = 0.f;
    }

    {
        const ushortT* vh = reinterpret_cast<const ushortT*>(ws + F_VH) + (size_t)b * N_ * 64;
        const ushortT* uh = reinterpret_cast<const ushortT*>(ws + F_UH) + (size_t)(b * N_ + q * 15) * 64;
        for (int idx = t; idx < 480; idx += 256) {
            int r = idx >> 3, c = (idx & 7) << 3;
            *reinterpret_cast<uint4*>(&sUVh[r * 72 + c]) =
                *reinterpret_cast<const uint4*>(&vh[(size_t)r * 64 + c]);
        }
        if (t < 120) {
            int r = t >> 3, c = (t & 7) << 3;
            *reinterpret_cast<uint4*>(&sUVh[(60 + r) * 72 + c]) =
                *reinterpret_cast<const uint4*>(&uh[(size_t)r * 64 + c]);
        }
    }
    if constexpr (STAGE == 2) {
        if (t < 64) {
            float S = 0.f, Q = 0.f;
            for (int s = 0; s < 64; ++s) {
                S += ws[G_ST2 + (size_t)s * 128 + t];
                Q += ws[G_ST2 + (size_t)s * 128 + 64 + t];
            }
            float inv = 1.f / (float)NETOT;
            float m = S * inv, var = Q * inv - m * m;
            float s_ = g2[t] * rsqrtf(var + EPS);
            sBN[t] = s_; sBN[64 + t] = be2[t] - m * s_;
        }
    }
    if (t < 128) red[t] = 0.f;

    // weight fragments -> registers (inline f32 -> fp16 conversion)
    f16x8 w2f0[4], w2f1[4], w3f0[2], w3f1[2];
    #pragma unroll
    for (int mu = 0; mu < 4; ++mu) {
        w2f0[mu] = ldf16(fr2_w + (size_t)(mu * 16 + ln) * 64 + gq * 8);
        w2f1[mu] = ldf16(fr2_w + (size_t)(mu * 16 + ln) * 64 + 32 + gq * 8);
    }
    if constexpr (STAGE == 2) {
        #pragma unroll
        for (int nv = 0; nv < 2; ++nv) {
            w3f0[nv] = ldf16(fr3_w + (size_t)(nv * 16 + ln) * 64 + gq * 8);
            w3f1[nv] = ldf16(fr3_w + (size_t)(nv * 16 + ln) * 64 + 32 + gq * 8);
        }
    }
    __syncthreads();

    if constexpr (STAGE == 1) {
        f32x4 s1s[4] = {zero, zero, zero, zero};
        f32x4 s1q[4] = {zero, zero, zero, zero};
        for (int gi = wv; gi < 15; gi += 4) {
            const int i = q * 15 + gi;
            uint4 uu0 = *reinterpret_cast<const uint4*>(&sUVh[(60 + gi) * 72 + gq * 8]);
            uint4 uu1 = *reinterpret_cast<const uint4*>(&sUVh[(60 + gi) * 72 + 32 + gq * 8]);
            #pragma unroll
            for (int m = 0; m < 4; ++m) {
                int e = (m << 4) + ln;
                int j = e + (e >= i ? 1 : 0);
                uint4 vv0 = *reinterpret_cast<const uint4*>(&sUVh[j * 72 + gq * 8]);
                uint4 vv1 = *reinterpret_cast<const uint4*>(&sUVh[j * 72 + 32 + gq * 8]);
                f16x8 ef0 = erelu(uu0, vv0, e < 59);
                f16x8 ef1 = erelu(uu1, vv1, e < 59);
                #pragma unroll
                for (int mu = 0; mu < 4; ++mu) {
                    f32x4 acc = __builtin_amdgcn_mfma_f32_16x16x32_f16(w2f0[mu], ef0, zero, 0, 0, 0);
                    acc = __builtin_amdgcn_mfma_f32_16x16x32_f16(w2f1[mu], ef1, acc, 0, 0, 0);
                    s1s[mu] += acc;
                    s1q[mu] += acc * acc;
                }
            }
        }
        #pragma unroll
        for (int off = 1; off <= 8; off <<= 1)
            #pragma unroll
            for (int mu = 0; mu < 4; ++mu)
                #pragma unroll
                for (int r = 0; r < 4; ++r) {
                    s1s[mu][r] += __shfl_xor(s1s[mu][r], off);
                    s1q[mu][r] += __shfl_xor(s1q[mu][r], off);
                }
        if (ln == 0) {
            #pragma unroll
            for (int mu = 0; mu < 4; ++mu)
                #pragma unroll
                for (int r = 0; r < 4; ++r) {
                    atomicAdd(&red[mu * 16 + gq * 4 + r], s1s[mu][r]);
                    atomicAdd(&red[64 + mu * 16 + gq * 4 + r], s1q[mu][r]);
                }
        }
        __syncthreads();
        if (t < 128) atomicAdd(ws + G_ST2 + (size_t)(blk & 63) * 128 + t, red[t]);
    } else {
        ushortT* scr = scrAll + wv * 2048;   // 2 regions x 1024 ushorts
        float st0 = 0.f, st1 = 0.f, st2 = 0.f, st3 = 0.f;
        ushortT* __restrict__ h3p = reinterpret_cast<ushortT*>(ws + F_H3);
        for (int gi = wv; gi < 15; gi += 4) {
            const int i = q * 15 + gi;
            const size_t ebase = ((size_t)b * NE + (size_t)i * 59) * 32;
            uint4 uu0 = *reinterpret_cast<const uint4*>(&sUVh[(60 + gi) * 72 + gq * 8]);
            uint4 uu1 = *reinterpret_cast<const uint4*>(&sUVh[(60 + gi) * 72 + 32 + gq * 8]);
            #pragma unroll
            for (int mp = 0; mp < 2; ++mp) {
                // ---- phase A: h2 + bn2relu + scatter for m = 2mp, 2mp+1 ----
                #pragma unroll
                for (int sub = 0; sub < 2; ++sub) {
                    const int m = mp * 2 + sub;
                    int e = (m << 4) + ln;
                    int j = e + (e >= i ? 1 : 0);
                    uint4 vv0 = *reinterpret_cast<const uint4*>(&sUVh[j * 72 + gq * 8]);
                    uint4 vv1 = *reinterpret_cast<const uint4*>(&sUVh[j * 72 + 32 + gq * 8]);
                    const bool eok = e < 59;
                    f16x8 ef0 = erelu(uu0, vv0, eok);
                    f16x8 ef1 = erelu(uu1, vv1, eok);
                    f32x4 ac[4];
                    #pragma unroll
                    for (int mu = 0; mu < 4; ++mu) {
                        ac[mu] = __builtin_amdgcn_mfma_f32_16x16x32_f16(w2f0[mu], ef0, zero, 0, 0, 0);
                        ac[mu] = __builtin_amdgcn_mfma_f32_16x16x32_f16(w2f1[mu], ef1, ac[mu], 0, 0, 0);
                    }
                    #pragma unroll
                    for (int mu = 0; mu < 4; ++mu) {
                        int fb = mu * 16 + (gq << 2);
                        float4 sc2 = *reinterpret_cast<const float4*>(sBN + fb);
                        float4 sh2 = *reinterpret_cast<const float4*>(sBN + 64 + fb);
                        unsigned int pk0 = cvtpk16(fmaxf(0.f, sc2.x * ac[mu][0] + sh2.x),
                                                   fmaxf(0.f, sc2.y * ac[mu][1] + sh2.y));
                        unsigned int pk1 = cvtpk16(fmaxf(0.f, sc2.z * ac[mu][2] + sh2.z),
                                                   fmaxf(0.f, sc2.w * ac[mu][3] + sh2.w));
                        if (!eok) { pk0 = 0u; pk1 = 0u; }
                        int lp = ln + ((((mu << 1) + (gq >> 1)) & 3) << 4);
                        int off = (sub << 10) + ((mu >> 1) << 9) + (lp << 3) + ((gq & 1) << 2);
                        uint2 pr; pr.x = pk0; pr.y = pk1;
                        *reinterpret_cast<uint2*>(&scr[off]) = pr;
                    }
                }
                __threadfence_block();
                // ---- phase B: gather + h3 for both subs ----
                #pragma unroll
                for (int sub = 0; sub < 2; ++sub) {
                    const int m = mp * 2 + sub;
                    union { uint4 q4; f16x8 v; } ea0, ea1;
                    ea0.q4 = *reinterpret_cast<const uint4*>(&scr[(sub << 10) + (lane << 3)]);
                    ea1.q4 = *reinterpret_cast<const uint4*>(&scr[(sub << 10) + 512 + (lane << 3)]);
                    f32x4 a30 = __builtin_amdgcn_mfma_f32_16x16x32_f16(ea0.v, w3f0[0], zero, 0, 0, 0);
                    a30 = __builtin_amdgcn_mfma_f32_16x16x32_f16(ea1.v, w3f1[0], a30, 0, 0, 0);
                    f32x4 a31 = __builtin_amdgcn_mfma_f32_16x16x32_f16(ea0.v, w3f0[1], zero, 0, 0, 0);
                    a31 = __builtin_amdgcn_mfma_f32_16x16x32_f16(ea1.v, w3f1[1], a31, 0, 0, 0);
                    // stats (pads contribute exact zeros) + h3 store
                    #pragma unroll
                    for (int r = 0; r < 4; ++r) {
                        st0 += a30[r]; st1 += a30[r] * a30[r];
                        st2 += a31[r]; st3 += a31[r] * a31[r];
                        int el = (m << 4) + (gq << 2) + r;
                        if (el < 59) {
                            size_t rb = ebase + (size_t)el * 32;
                            h3p[rb + ln] = (ushortT)(cvtpk16(a30[r], 0.f) & 0xffffu);
                            h3p[rb + 16 + ln] = (ushortT)(cvtpk16(a31[r], 0.f) & 0xffffu);
                        }
                    }
                }
            }
        }
        st0 += __shfl_xor(st0, 16); st0 += __shfl_xor(st0, 32);
        st1 += __shfl_xor(st1, 16); st1 += __shfl_xor(st1, 32);
        st2 += __shfl_xor(st2, 16); st2 += __shfl_xor(st2, 32);
        st3 += __shfl_xor(st3, 16); st3 += __shfl_xor(st3, 32);
        if (lane < 16) {
            atomicAdd(&red[ln], st0);      atomicAdd(&red[16 + ln], st2);
            atomicAdd(&red[32 + ln], st1); atomicAdd(&red[48 + ln], st3);
        }
        __syncthreads();
        if (t < 64) atomicAdd(ws + G_ST3 + (size_t)(blk & 63) * 64 + t, red[t]);
    }
}

// ---- K8: stream h3; inline bn3 finalize; relu; segment-sum -> EBAR; zero G_SO2 ----
__global__ __launch_bounds__(256) void k8_scatter(const float* __restrict__ g3,
                                                  const float* __restrict__ be3,
                                                  float* __restrict__ ws) {
    __shared__ float sc3[32], sh3[32];
    const int t = threadIdx.x;
    if ((int)blockIdx.x < 16 && t < 128)
        ws[G_SO2 + (size_t)blockIdx.x * 128 + t] = 0.f;
    if (t < 32) {
        float S = 0.f, Q = 0.f;
        for (int s = 0; s < 64; ++s) {
            S += ws[G_ST3 + (size_t)s * 64 + t];
            Q += ws[G_ST3 + (size_t)s * 64 + 32 + t];
        }
        float inv = 1.f / (float)NETOT;
        float m = S * inv, var = Q * inv - m * m;
        float sc = g3[t] * rsqrtf(var + EPS);
        sc3[t] = sc; sh3[t] = be3[t] - m * sc;
    }
    __syncthreads();
    const int wv = t >> 6, lane = t & 63;
    const int fp = lane & 15, h = lane >> 4;       // f pair index, row phase
    const int grp = blockIdx.x * 4 + wv;           // (b,i) group
    const int b = grp / N_, i = grp - b * N_;
    const unsigned int* __restrict__ h3u =
        reinterpret_cast<const unsigned int*>(ws + F_H3) + ((size_t)b * NE + (size_t)i * 59) * 16;
    const int f0 = fp * 2;
    const float s0 = sc3[f0], s1 = sc3[f0 + 1];
    const float t0 = sh3[f0], t1 = sh3[f0 + 1];
    float a0 = 0.f, a1 = 0.f;
    for (int r = h; r < 59; r += 4) {
        union { unsigned int u; __fp16 hh[2]; } v;
        v.u = h3u[(size_t)r * 16 + fp];
        a0 += fmaxf(0.f, s0 * (float)v.hh[0] + t0);
        a1 += fmaxf(0.f, s1 * (float)v.hh[1] + t1);
    }
    a0 += __shfl_xor(a0, 16); a0 += __shfl_xor(a0, 32);
    a1 += __shfl_xor(a1, 16); a1 += __shfl_xor(a1, 32);
    if (h == 0) {
        float2 r2; r2.x = a0; r2.y = a1;
        *reinterpret_cast<float2*>(ws + F_EBAR + (size_t)grp * 32 + f0) = r2;
    }
}

// ---- object-path linear; optional inline BN finalize (16-slot sum); slotted output stats ----
template <int OUT, int FIN>
__global__ __launch_bounds__(256) void kobj(const float* __restrict__ srcA,
                                            const float* __restrict__ srcB,
                                            const float* __restrict__ statIn,
                                            const float* __restrict__ gP,
                                            const float* __restrict__ beP,
                                            const float* __restrict__ W,
                                            float* __restrict__ outp,
                                            float* __restrict__ statOut,
                                            float* __restrict__ zeroPtr,
                                            int zeroCnt) {
    constexpr int TRN = (OUT == 64) ? 16 : 32;
    constexpr int RB = 4 * TRN;
    constexpr int SP = RB + 4;
    constexpr int WP = OUT + 4;
    __shared__ __align__(16) float sinT[64 * SP];
    __shared__ __align__(16) float swt[64 * WP];
    __shared__ float sAct[128];
    const int t = threadIdx.x;
    const int row0 = blockIdx.x * RB;
    if (zeroPtr && (int)blockIdx.x < 16 && t < zeroCnt)
        zeroPtr[(size_t)blockIdx.x * zeroCnt + t] = 0.f;
    if (FIN > 0 && t < 64) {
        float S = 0.f, Q = 0.f;
        #pragma unroll
        for (int s = 0; s < 16; ++s) {
            S += statIn[(size_t)s * 128 + t];
            Q += statIn[(size_t)s * 128 + 64 + t];
        }
        float inv = 1.f / (float)ROWS;
        float m = S * inv, var = Q * inv - m * m;
        float sc = gP[t] * rsqrtf(var + EPS);
        sAct[t] = sc; sAct[64 + t] = beP[t] - m * sc;
    }
    __syncthreads();
    for (int idx = t; idx < RB * 64; idx += 256) {
        int r = idx % RB, k = idx / RB;
        float v;
        if (srcB) {
            v = (k < 32) ? srcA[(size_t)(row0 + r) * 32 + k]
                         : srcB[(size_t)(row0 + r) * 32 + (k - 32)];
        } else {
            v = srcA[(size_t)(row0 + r) * 64 + k];
        }
        if (FIN > 0) v = fmaxf(0.f, sAct[k] * v + sAct[64 + k]);
        sinT[k * SP + r] = v;
    }
    for (int idx = t; idx < OUT * 64; idx += 256) {
        int o = idx >> 6, k = idx & 63;
        swt[k * WP + o] = W[idx];
    }
    __syncthreads();
    const int tr = t % TRN, to = t / TRN;
    const int r0 = tr * 4, o0 = to * 4;
    float acc[4][4];
    #pragma unroll
    for (int a = 0; a < 4; ++a)
        #pragma unroll
        for (int c = 0; c < 4; ++c) acc[a][c] = 0.f;
    #pragma unroll 8
    for (int k = 0; k < 64; ++k) {
        float4 a4 = *reinterpret_cast<const float4*>(sinT + k * SP + r0);
        float4 w4 = *reinterpret_cast<const float4*>(swt + k * WP + o0);
        float av[4] = {a4.x, a4.y, a4.z, a4.w};
        float wv[4] = {w4.x, w4.y, w4.z, w4.w};
        #pragma unroll
        for (int a = 0; a < 4; ++a)
            #pragma unroll
            for (int c = 0; c < 4; ++c) acc[a][c] += av[a] * wv[c];
    }
    float lsum[4] = {0.f, 0.f, 0.f, 0.f}, lsq[4] = {0.f, 0.f, 0.f, 0.f};
    #pragma unroll
    for (int a = 0; a < 4; ++a) {
        float4 res;
        res.x = acc[a][0]; res.y = acc[a][1]; res.z = acc[a][2]; res.w = acc[a][3];
        #pragma unroll
        for (int c = 0; c < 4; ++c) { lsum[c] += acc[a][c]; lsq[c] += acc[a][c] * acc[a][c]; }
        *reinterpret_cast<float4*>(outp + (size_t)(row0 + r0 + a) * OUT + o0) = res;
    }
    #pragma unroll
    for (int o = TRN / 2; o >= 1; o >>= 1) {
        #pragma unroll
        for (int c = 0; c < 4; ++c) {
            lsum[c] += __shfl_down(lsum[c], o, TRN);
            lsq[c]  += __shfl_down(lsq[c], o, TRN);
        }
    }
    if (tr == 0) {
        float* so = statOut + (size_t)(blockIdx.x & 15) * (2 * OUT);
        #pragma unroll
        for (int c = 0; c < 4; ++c) {
            atomicAdd(so + o0 + c, lsum[c]);
            atomicAdd(so + OUT + o0 + c, lsq[c]);
        }
    }
}

// ---- K15: inline fin3 (16-slot sum); relu(bn(ho3)); pool; fc ----
__global__ __launch_bounds__(64) void k15_final(const float* __restrict__ g,
                                                const float* __restrict__ be,
                                                const float* __restrict__ fcw,
                                                const float* __restrict__ fcb,
                                                float* __restrict__ ws,
                                                float* __restrict__ out) {
    __shared__ float sc3s[32], sh3s[32];
    int b = blockIdx.x, t = threadIdx.x;
    if (t < 32) {
        float S = 0.f, Q = 0.f;
        #pragma unroll
        for (int s = 0; s < 16; ++s) {
            S += ws[G_SO3 + (size_t)s * 64 + t];
            Q += ws[G_SO3 + (size_t)s * 64 + 32 + t];
        }
        float inv = 1.f / (float)ROWS;
        float m = S * inv, var = Q * inv - m * m;
        float sc = g[t] * rsqrtf(var + EPS);
        sc3s[t] = sc; sh3s[t] = be[t] - m * sc;
    }
    __syncthreads();
    int f = t & 31, h = t >> 5;
    float sc = sc3s[f], sh = sh3s[f];
    float acc = 0.f;
    for (int n = h; n < N_; n += 2) {
        float v = ws[F_HO3 + (size_t)(b * N_ + n) * 32 + f];
        acc += fmaxf(0.f, sc * v + sh);
    }
    acc += __shfl_down(acc, 32);
    float p0 = acc * fcw[f];
    float p1 = acc * fcw[32 + f];
    #pragma unroll
    for (int o = 16; o >= 1; o >>= 1) {
        p0 += __shfl_xor(p0, o);
        p1 += __shfl_xor(p1, o);
    }
    if (t == 0) {
        out[b * 2 + 0] = p0 + fcb[0];
        out[b * 2 + 1] = p1 + fcb[1];
    }
}

extern "C" void kernel_launch(void* const* d_in, const int* in_sizes, int n_in,
                              void* d_out, int out_size, void* d_ws, size_t ws_size,
                              hipStream_t stream) {
    const float* x      = (const float*)d_in[0];
    const float* bnx_g  = (const float*)d_in[1];
    const float* bnx_b  = (const float*)d_in[2];
    const float* fr1_w  = (const float*)d_in[3];
    const float* fr1_g  = (const float*)d_in[5];
    const float* fr1_be = (const float*)d_in[6];
    const float* fr2_w  = (const float*)d_in[7];
    const float* fr2_g  = (const float*)d_in[9];
    const float* fr2_be = (const float*)d_in[10];
    const float* fr3_w  = (const float*)d_in[11];
    const float* fr3_g  = (const float*)d_in[13];
    const float* fr3_be = (const float*)d_in[14];
    const float* fo1_w  = (const float*)d_in[15];
    const float* fo1_g  = (const float*)d_in[17];
    const float* fo1_be = (const float*)d_in[18];
    const float* fo2_w  = (const float*)d_in[19];
    const float* fo2_g  = (const float*)d_in[21];
    const float* fo2_be = (const float*)d_in[22];
    const float* fo3_w  = (const float*)d_in[23];
    const float* fo3_g  = (const float*)d_in[25];
    const float* fo3_be = (const float*)d_in[26];
    const float* fc_w   = (const float*)d_in[27];
    const float* fc_b   = (const float*)d_in[28];

    float* ws = (float*)d_ws;
    float* out = (float*)d_out;
    if (ws_size < F_TOTAL * sizeof(float)) return;

    k0_part<<<256, 256, 0, stream>>>(x, ws);
    k1_uv<<<B_, 256, 0, stream>>>(x, fr1_w, bnx_g, bnx_b, ws);
    k3b<<<480, 256, 0, stream>>>(fr1_g, fr1_be, ws);
    kedge<1><<<B_ * 4, 256, 0, stream>>>(fr2_w, fr3_w, fr2_g, fr2_be, ws);
    kedge<2><<<B_ * 4, 256, 0, stream>>>(fr2_w, fr3_w, fr2_g, fr2_be, ws);
    k8_scatter<<<ROWS / 4, 256, 0, stream>>>(fr3_g, fr3_be, ws);
    kobj<64, 0><<<ROWS / 64, 256, 0, stream>>>(ws + F_XT, ws + F_EBAR, nullptr, nullptr, nullptr,
                                               fo1_w, ws + F_HO1, ws + G_SO1, ws + G_SO3, 64);
    kobj<64, 64><<<ROWS / 64, 256, 0, stream>>>(ws + F_HO1, nullptr, ws + G_SO1, fo1_g, fo1_be,
                                                fo2_w, ws + F_HO2, ws + G_SO2, nullptr, 0);
    kobj<32, 64><<<ROWS / 128, 256, 0, stream>>>(ws + F_HO2, nullptr, ws + G_SO2, fo2_g, fo2_be,
                                                 fo3_w, ws + F_HO3, ws + G_SO3, nullptr, 0);
    k15_final<<<B_, 64, 0, stream>>>(fo3_g, fo3_be, fc_w, fc_b, ws, out);
}